// Round 3
// baseline (408.871 us; speedup 1.0000x reference)
//
#include <hip/hip_runtime.h>

#define N_NODES 100000
#define N_EDGES 3200000
#define C_IN 256
#define C_H 64
#define C_OUT 128
#define NB 391       // ceil(N_NODES/256) buckets of 256 nodes
#define G2F 625      // blocks for fused gemm2+pool
#define NTILES 6250  // N_NODES/16
#define NT16 6250    // gather tiles of 16 nodes
#define G_GM 1563    // ceil(NT16/4)
#define CH1 8192     // edges per block in hist/scatter1

typedef unsigned int u32;
typedef unsigned short u16;
typedef unsigned long long u64;
typedef __attribute__((ext_vector_type(8))) short bf16x8;
typedef __attribute__((ext_vector_type(4))) float f32x4;

typedef __attribute__((address_space(3))) unsigned int l_u32;
typedef __attribute__((address_space(1))) const unsigned int g_u32;

// ---------- bf16 helpers ----------
__device__ __forceinline__ float bflo(u32 p) {
    union { u32 i; float f; } v; v.i = p << 16; return v.f;
}
__device__ __forceinline__ float bfhi(u32 p) {
    union { u32 i; float f; } v; v.i = p & 0xffff0000u; return v.f;
}
__device__ __forceinline__ float bf2f(u16 u) {
    union { u32 i; float f; } v; v.i = ((u32)u) << 16; return v.f;
}
__device__ __forceinline__ u16 f2bf(float f) {
    union { float f; u32 i; } v; v.f = f;
    u32 x = v.i;
    return (u16)((x + 0x7fffu + ((x >> 16) & 1u)) >> 16);  // RNE
}

__device__ __forceinline__ void gll16(const void* gp, const u16* lp) {
    __builtin_amdgcn_global_load_lds((g_u32*)gp, (l_u32*)lp, 16, 0, 0);
}

// ---------- slim detection: flags + small tensors ----------
__global__ void k_detect(const void* __restrict__ x, const void* __restrict__ ei,
                         const void* __restrict__ b1, const void* __restrict__ b2,
                         const void* __restrict__ fcW, const void* __restrict__ fcb,
                         int* __restrict__ flags,
                         float* __restrict__ b1c, float* __restrict__ b2c,
                         float* __restrict__ fcWc, float* __restrict__ fcbc) {
    __shared__ int sf[2];
    int t = threadIdx.x;
    if (t < 64) {
        u32 w = ((const u32*)x)[t];
        u32 low = w & 0xffffu;
        int e = (int)((low >> 7) & 0xff);
        bool inw = (e > 96 && e < 160) || (low == 0);
        u64 m = __ballot(inw);
        if (t == 0) sf[0] = (__popcll(m) >= 60) ? 1 : 0;
    } else if (t < 128) {
        int i = t - 64;
        u32 w = ((const u32*)ei)[2 * i + 1];
        u64 m = __ballot(w == 0);
        if (i == 0) sf[1] = (m == ~0ull) ? 1 : 0;
    }
    __syncthreads();
    if (t == 0) { flags[0] = sf[0]; flags[1] = sf[1]; }
    int isbf = sf[0];
    if (isbf) {
        const u16* p1 = (const u16*)b1;  const u16* p2 = (const u16*)b2;
        const u16* pw = (const u16*)fcW; const u16* pb = (const u16*)fcb;
        for (int i = t; i < C_H; i += 256) b1c[i] = bf2f(p1[i]);
        for (int i = t; i < C_OUT; i += 256) b2c[i] = bf2f(p2[i]);
        for (int i = t; i < 2 * C_OUT; i += 256) fcWc[i] = bf2f(pw[i]);
        for (int i = t; i < 2; i += 256) fcbc[i] = bf2f(pb[i]);
    } else {
        const float* p1 = (const float*)b1;  const float* p2 = (const float*)b2;
        const float* pw = (const float*)fcW; const float* pb = (const float*)fcb;
        for (int i = t; i < C_H; i += 256) b1c[i] = p1[i];
        for (int i = t; i < C_OUT; i += 256) b2c[i] = p2[i];
        for (int i = t; i < 2 * C_OUT; i += 256) fcWc[i] = pw[i];
        for (int i = t; i < 2; i += 256) fcbc[i] = pb[i];
    }
}

// ---------- parallel prep: W1m/W2m frag-order swizzles + bucket_cnt zero ----------
__global__ __launch_bounds__(256) void k_prep(const void* __restrict__ W1,
                                              const void* __restrict__ W2,
                                              const int* __restrict__ flags,
                                              u16* __restrict__ W1m, u16* __restrict__ W2m,
                                              u32* __restrict__ bucket_cnt) {
    int b = blockIdx.x, t = threadIdx.x;
    int isbf = flags[0];
    int i = b * 256 + t;
    if (i < NB) bucket_cnt[i] = 0;
    if (i < C_IN * C_H) {
        const u16* w1b = (const u16*)W1; const float* w1f = (const float*)W1;
        int j = i & 7, lane = (i >> 3) & 63, nt = (i >> 9) & 3, k0 = i >> 11;
        int k = k0 * 32 + ((lane >> 4) & 3) * 8 + j;
        int n = nt * 16 + (lane & 15);
        W1m[i] = isbf ? w1b[k * C_H + n] : f2bf(w1f[k * C_H + n]);
    } else {
        int i2 = i - C_IN * C_H;
        const u16* w2b = (const u16*)W2; const float* w2f = (const float*)W2;
        int j = i2 & 7, lane = (i2 >> 3) & 63, nt = (i2 >> 9) & 7, k0 = (i2 >> 12) & 1;
        int k = k0 * 32 + ((lane >> 4) & 3) * 8 + j;
        int n = nt * 16 + (lane & 15);
        W2m[i2] = isbf ? w2b[k * C_OUT + n] : f2bf(w2f[k * C_OUT + n]);
    }
}

// ---------- bucket histogram over dst>>8 ----------
__global__ __launch_bounds__(256) void k_hist1(const int* __restrict__ ei,
                                               const int* __restrict__ flags,
                                               u32* __restrict__ bucket_cnt) {
    __shared__ u32 h[NB];
    int t = threadIdx.x;
    int is64 = flags[1];
    for (int i = t; i < NB; i += 256) h[i] = 0;
    __syncthreads();
    int e0 = blockIdx.x * CH1;
    int nv = min(CH1, N_EDGES - e0);
    for (int i = t; i < nv; i += 256) {
        int e = e0 + i;
        int d = is64 ? ei[2 * (N_EDGES + e)] : ei[N_EDGES + e];
        atomicAdd(&h[d >> 8], 1u);
    }
    __syncthreads();
    for (int i = t; i < NB; i += 256)
        if (h[i]) atomicAdd(&bucket_cnt[i], h[i]);
}

// ---------- scan bucket counts -> base + cursor ----------
__global__ __launch_bounds__(512) void k_bscan(const u32* __restrict__ bucket_cnt,
                                               u32* __restrict__ bucket_base,
                                               u32* __restrict__ bucket_cursor,
                                               int* __restrict__ rowptr) {
    __shared__ u32 sm[512];
    int t = threadIdx.x;
    u32 v = (t < NB) ? bucket_cnt[t] : 0;
    sm[t] = v;
    __syncthreads();
    for (int off = 1; off < 512; off <<= 1) {
        u32 a = (t >= off) ? sm[t - off] : 0;
        __syncthreads();
        sm[t] += a;
        __syncthreads();
    }
    if (t < NB) {
        u32 excl = sm[t] - v;
        bucket_base[t] = excl;
        bucket_cursor[t] = excl;
    }
    if (t == 0) bucket_base[NB] = N_EDGES;
    (void)rowptr;
}

// ---------- pass 1: bucket-sorted staged scatter (line-dense writes) ----------
__global__ __launch_bounds__(512) void k_scatter1(const int* __restrict__ ei,
                                                  const int* __restrict__ flags,
                                                  u32* __restrict__ bucket_cursor,
                                                  u32* __restrict__ ebuf) {
    __shared__ u32 cnt[NB];
    __shared__ u32 lcur[NB];
    __shared__ u32 gbase[NB];
    __shared__ u32 lofs[512];
    __shared__ u32 stp[CH1];
    __shared__ u16 stb[CH1];
    int t = threadIdx.x;
    int is64 = flags[1];
    int e0 = blockIdx.x * CH1;
    int nv = min(CH1, N_EDGES - e0);
    for (int i = t; i < NB; i += 512) { cnt[i] = 0; lcur[i] = 0; }
    __syncthreads();
    for (int i = t; i < nv; i += 512) {
        int e = e0 + i;
        int d = is64 ? ei[2 * (N_EDGES + e)] : ei[N_EDGES + e];
        atomicAdd(&cnt[d >> 8], 1u);
    }
    __syncthreads();
    u32 v = (t < NB) ? cnt[t] : 0;
    lofs[t] = v;
    __syncthreads();
    for (int off = 1; off < 512; off <<= 1) {
        u32 a = (t >= off) ? lofs[t - off] : 0;
        __syncthreads();
        lofs[t] += a;
        __syncthreads();
    }
    u32 excl = lofs[t] - v;
    __syncthreads();
    lofs[t] = excl;
    __syncthreads();
    for (int i = t; i < nv; i += 512) {
        int e = e0 + i;
        int d, s;
        if (is64) { d = ei[2 * (N_EDGES + e)]; s = ei[2 * e]; }
        else      { d = ei[N_EDGES + e];       s = ei[e]; }
        int b = d >> 8;
        u32 slot = lofs[b] + atomicAdd(&lcur[b], 1u);
        stp[slot] = ((u32)(d & 255) << 20) | (u32)s;
        stb[slot] = (u16)b;
    }
    __syncthreads();
    for (int b = t; b < NB; b += 512) {
        u32 c = cnt[b];
        gbase[b] = c ? atomicAdd(&bucket_cursor[b], c) : 0;
    }
    __syncthreads();
    for (int s = t; s < nv; s += 512) {
        int b = stb[s];
        ebuf[gbase[b] + (s - lofs[b])] = stp[s];
    }
}

// ---------- pass 2: per-bucket local sort -> csr (byte offsets, WITH self-loops) ----------
// csr row for node n: [rowptr[n], rowptr[n+1]) ; first entry = self (n*128),
// then the in-edges' src byte offsets (src*128). rowptr[N] set by last node.
__global__ __launch_bounds__(256) void k_scatter2(const u32* __restrict__ bucket_base,
                                                  const u32* __restrict__ ebuf,
                                                  int* __restrict__ rowptr,
                                                  float* __restrict__ dinv,
                                                  int* __restrict__ csr) {
    __shared__ int cnt[256];
    __shared__ int pfx[256];
    __shared__ int lcur[256];
    int b = blockIdx.x, t = threadIdx.x;
    int ebeg = (int)bucket_base[b], eend = (int)bucket_base[b + 1];
    int sbeg = ebeg + (b << 8);   // +1 self slot per node in prior (full) buckets
    cnt[t] = 0;
    lcur[t] = 0;
    __syncthreads();
    for (int i = ebeg + t; i < eend; i += 256)
        atomicAdd(&cnt[(ebuf[i] >> 20) & 255], 1);
    __syncthreads();
    int v = cnt[t];
    pfx[t] = v;
    __syncthreads();
    for (int off = 1; off < 256; off <<= 1) {
        int a = (t >= off) ? pfx[t - off] : 0;
        __syncthreads();
        pfx[t] += a;
        __syncthreads();
    }
    int node = (b << 8) + t;
    int rstart = sbeg + (pfx[t] - v) + t;
    if (node < N_NODES) {
        rowptr[node] = rstart;
        dinv[node] = rsqrtf((float)(v + 1));
        csr[rstart] = node << 7;            // self-loop, byte offset
        if (node == N_NODES - 1) {
            rowptr[N_NODES] = rstart + v + 1;
            for (int i = 0; i < 64; ++i) csr[rstart + v + 1 + i] = 0;  // chunk-overrun pad
        }
    }
    __syncthreads();
    for (int i = ebeg + t; i < eend; i += 256) {
        u32 p = ebuf[i];
        int dl = (p >> 20) & 255;
        int pos = sbeg + (pfx[dl] - cnt[dl]) + dl + 1 + atomicAdd(&lcur[dl], 1);
        csr[pos] = (int)((p & 0x1FFFFu) << 7);   // src byte offset
    }
}

// ---------- MFMA GEMM1: g1[N,64] = dinv ⊙ (x[N,256] @ W1[256,64]) ----------
__global__ __launch_bounds__(256) void k_gemm1(const void* __restrict__ xv,
                                               const u16* __restrict__ W1m,
                                               const float* __restrict__ dinv,
                                               u16* __restrict__ g1,
                                               const int* __restrict__ flags) {
    __shared__ u16 wlds[C_IN * C_H];   // 32 KB
    int t = threadIdx.x;
    int isbf = flags[0];
    {
        const uint4* src = (const uint4*)W1m;
        uint4* dst = (uint4*)wlds;
#pragma unroll
        for (int it = 0; it < 8; ++it) dst[t + it * 256] = src[t + it * 256];
    }
    __syncthreads();
    int w = t >> 6, lane = t & 63;
    int quad = lane >> 4, mrow = lane & 15;
    int m0 = blockIdx.x * 128 + w * 32;
    if (m0 >= N_NODES) return;

    bf16x8 a[2][8];
    if (isbf) {
        const u16* xb = (const u16*)xv;
#pragma unroll
        for (int mt = 0; mt < 2; ++mt)
#pragma unroll
            for (int k0 = 0; k0 < 8; ++k0)
                a[mt][k0] = *(const bf16x8*)(xb + (size_t)(m0 + mt * 16 + mrow) * C_IN + k0 * 32 + quad * 8);
    } else {
        const float* xf = (const float*)xv;
#pragma unroll
        for (int mt = 0; mt < 2; ++mt)
#pragma unroll
            for (int k0 = 0; k0 < 8; ++k0) {
                const float* p = xf + (size_t)(m0 + mt * 16 + mrow) * C_IN + k0 * 32 + quad * 8;
                float4 v0 = *(const float4*)p;
                float4 v1 = *(const float4*)(p + 4);
                bf16x8 r;
                r[0] = (short)f2bf(v0.x); r[1] = (short)f2bf(v0.y);
                r[2] = (short)f2bf(v0.z); r[3] = (short)f2bf(v0.w);
                r[4] = (short)f2bf(v1.x); r[5] = (short)f2bf(v1.y);
                r[6] = (short)f2bf(v1.z); r[7] = (short)f2bf(v1.w);
                a[mt][k0] = r;
            }
    }

    float dv0[4], dv1[4];
#pragma unroll
    for (int r = 0; r < 4; ++r) {
        dv0[r] = dinv[m0 + quad * 4 + r];
        dv1[r] = dinv[m0 + 16 + quad * 4 + r];
    }

#pragma unroll
    for (int nt = 0; nt < 4; ++nt) {
        bf16x8 b[8];
#pragma unroll
        for (int k0 = 0; k0 < 8; ++k0)
            b[k0] = *(const bf16x8*)&wlds[((k0 * 4 + nt) * 64 + lane) * 8];
        f32x4 acc0 = {0.f, 0.f, 0.f, 0.f};
        f32x4 acc1 = {0.f, 0.f, 0.f, 0.f};
#pragma unroll
        for (int k0 = 0; k0 < 8; ++k0) {
            acc0 = __builtin_amdgcn_mfma_f32_16x16x32_bf16(a[0][k0], b[k0], acc0, 0, 0, 0);
            acc1 = __builtin_amdgcn_mfma_f32_16x16x32_bf16(a[1][k0], b[k0], acc1, 0, 0, 0);
        }
        int ch = nt * 16 + mrow;   // D: col = lane&15
#pragma unroll
        for (int r = 0; r < 4; ++r) {   // D: row = quad*4 + r
            g1[(size_t)(m0 + quad * 4 + r) * C_H + ch] = f2bf(acc0[r] * dv0[r]);
            g1[(size_t)(m0 + 16 + quad * 4 + r) * C_H + ch] = f2bf(acc1[r] * dv1[r]);
        }
    }
}

// ---------- MFMA gather: out[16-node tile] = Sel(32 edges) x G(32 rows), chunked ----------
// One wave per 16-node tile. CSR (dst-sorted, self-loops included) streamed in
// 32-edge chunks. Pipeline: csr addrs loaded 2 chunks ahead (regs), rows staged
// 1 chunk ahead (gll -> alt LDS buffer); single vmcnt(0) at iteration top gives
// both a full compute-phase of latency cover. Staging (lane l): edge it*8+(l>>3),
// channel octet l&7. Fragments via plain ds_read_u16 (deterministic). Selector
// computed arithmetically (no LDS LUT -> 32KB block LDS -> 5 blocks/CU).
// MODE 0: out = bf16(dinv * relu(dinv*sum + bias))   MODE 1: out = bf16(dinv*sum)
template <int MODE>
__global__ __launch_bounds__(256) void k_gatherM(const int* __restrict__ rowptr,
                                                 const int* __restrict__ csrb,
                                                 const float* __restrict__ dinv,
                                                 const u16* __restrict__ gt,
                                                 const float* __restrict__ bias,
                                                 u16* __restrict__ out) {
    __shared__ __align__(16) u16 hs[4][4096];   // per wave: 2 buffers x 4KB (32KB total)
    int t = threadIdx.x;
    int w = t >> 6, lane = t & 63;
    int tile = blockIdx.x * 4 + w;
    if (tile >= NT16) return;

    int g16 = lane >> 4, c = lane & 15;
    int n0 = tile << 4;
    int lo = rowptr[n0 + c];
    int hi = rowptr[n0 + c + 1];
    int beg = __shfl(lo, 0, 64);
    int end = __shfl(hi, 15, 64);
    int eidx = lane >> 3;            // edge-in-slice staged by this lane
    int boff = (lane & 7) * 16;      // byte offset (channel octet) within row
    const char* gb = (const char*)gt;
    f32x4 acc0 = {0.f, 0.f, 0.f, 0.f}, acc1 = acc0, acc2 = acc0, acc3 = acc0;
    int nch = (end - beg + 31) >> 5;
    int cb = beg;
    // prologue: c0 addrs (used immediately), c1 addrs ahead, stage c0
    u32 p0 = (u32)csrb[cb + eidx];
    u32 p1 = (u32)csrb[cb + 8 + eidx];
    u32 p2 = (u32)csrb[cb + 16 + eidx];
    u32 p3 = (u32)csrb[cb + 24 + eidx];
    asm volatile("" ::: "memory");
    u32 q0 = 0, q1 = 0, q2 = 0, q3 = 0;
    if (nch > 1) {
        q0 = (u32)csrb[cb + 32 + eidx];
        q1 = (u32)csrb[cb + 40 + eidx];
        q2 = (u32)csrb[cb + 48 + eidx];
        q3 = (u32)csrb[cb + 56 + eidx];
    }
    asm volatile("" ::: "memory");
    gll16(gb + p0 + boff, &hs[w][0]);
    gll16(gb + p1 + boff, &hs[w][512]);
    gll16(gb + p2 + boff, &hs[w][1024]);
    gll16(gb + p3 + boff, &hs[w][1536]);
    asm volatile("" ::: "memory");
    for (int ci = 0; ci < nch; ++ci) {
        bool more1 = ci + 1 < nch;
        bool more2 = ci + 2 < nch;
        // gll(ci) had the previous compute phase to land; csr(ci+1) likewise.
        asm volatile("s_waitcnt vmcnt(0)" ::: "memory");
        if (more1) {                                  // stage chunk ci+1, other buffer
            int bo = ((ci + 1) & 1) << 11;
            gll16(gb + q0 + boff, &hs[w][bo]);
            gll16(gb + q1 + boff, &hs[w][bo + 512]);
            gll16(gb + q2 + boff, &hs[w][bo + 1024]);
            gll16(gb + q3 + boff, &hs[w][bo + 1536]);
        }
        asm volatile("" ::: "memory");
        if (more2) {                                  // csr addrs for chunk ci+2
            q0 = (u32)csrb[cb + 64 + eidx];
            q1 = (u32)csrb[cb + 72 + eidx];
            q2 = (u32)csrb[cb + 80 + eidx];
            q3 = (u32)csrb[cb + 88 + eidx];
        }
        asm volatile("" ::: "memory");
        // fragment assembly: lane (c,g16), element (j,cht) at
        // buf + g16*1024 + j*128 + cht*32 + (c>>3)*16 + (c&7)*2   [bytes]
        const u16* lp = &hs[w][((ci & 1) << 11) + g16 * 512 + ((c >> 3) << 3) + (c & 7)];
        bf16x8 bfr[4];
#pragma unroll
        for (int cht = 0; cht < 4; ++cht) {
            u32 w0 = (u32)lp[0 * 64 + cht * 16] | ((u32)lp[1 * 64 + cht * 16] << 16);
            u32 w1 = (u32)lp[2 * 64 + cht * 16] | ((u32)lp[3 * 64 + cht * 16] << 16);
            u32 w2 = (u32)lp[4 * 64 + cht * 16] | ((u32)lp[5 * 64 + cht * 16] << 16);
            u32 w3 = (u32)lp[6 * 64 + cht * 16] | ((u32)lp[7 * 64 + cht * 16] << 16);
            union { u32 u[4]; bf16x8 v; } z;
            z.u[0] = w0; z.u[1] = w1; z.u[2] = w2; z.u[3] = w3;
            bfr[cht] = z.v;
        }
        int cbg = cb + g16 * 8;
        int s0 = min(max(lo - cbg, 0), 8);
        int e0 = min(max(hi - cbg, 0), 8);
        bf16x8 af;
#pragma unroll
        for (int j = 0; j < 8; ++j)
            af[j] = (short)((j >= s0 && j < e0) ? 0x3F80 : 0);
        acc0 = __builtin_amdgcn_mfma_f32_16x16x32_bf16(af, bfr[0], acc0, 0, 0, 0);
        acc1 = __builtin_amdgcn_mfma_f32_16x16x32_bf16(af, bfr[1], acc1, 0, 0, 0);
        acc2 = __builtin_amdgcn_mfma_f32_16x16x32_bf16(af, bfr[2], acc2, 0, 0, 0);
        acc3 = __builtin_amdgcn_mfma_f32_16x16x32_bf16(af, bfr[3], acc3, 0, 0, 0);
        cb += 32;
    }
    // epilogue: D row = node (lane>>4)*4+r, D col = channel cht*16 + (lane&15)
    float dv[4];
    int nb = n0 + g16 * 4;
#pragma unroll
    for (int r = 0; r < 4; ++r) dv[r] = dinv[nb + r];
    u16* ob = out + (size_t)nb * C_H + c;
#define EPI(ACC, CHT)                                                              \
    {                                                                              \
        float bs = (MODE == 0) ? bias[CHT * 16 + c] : 0.f;                         \
        _Pragma("unroll")                                                          \
        for (int r = 0; r < 4; ++r) {                                              \
            float val = (MODE == 0) ? dv[r] * fmaxf(dv[r] * ACC[r] + bs, 0.f)      \
                                    : dv[r] * ACC[r];                              \
            ob[r * C_H + CHT * 16] = f2bf(val);                                    \
        }                                                                          \
    }
    EPI(acc0, 0) EPI(acc1, 1) EPI(acc2, 2) EPI(acc3, 3)
#undef EPI
}

// ---------- fused MFMA GEMM2 + bias + relu + mean-pool partials ----------
__global__ __launch_bounds__(256) void k_fused2(const u16* __restrict__ aggb,
                                                const u16* __restrict__ W2m,
                                                const float* __restrict__ b2c,
                                                float* __restrict__ partial) {
    __shared__ float psum[4 * 8 * 64];   // [wave][nt][lane], 8 KB
    int t = threadIdx.x;
    int w = t >> 6, lane = t & 63;
    int quad = lane >> 4, m = lane & 15;

    bf16x8 b[2][8];
#pragma unroll
    for (int k0 = 0; k0 < 2; ++k0)
#pragma unroll
        for (int nt = 0; nt < 8; ++nt)
            b[k0][nt] = *(const bf16x8*)&W2m[((k0 * 8 + nt) * 64 + lane) * 8];

    float pacc[8] = {0.f, 0.f, 0.f, 0.f, 0.f, 0.f, 0.f, 0.f};
    float bias[8];
#pragma unroll
    for (int nt = 0; nt < 8; ++nt) bias[nt] = b2c[nt * 16 + m];

    for (int tile = blockIdx.x * 4 + w; tile < NTILES; tile += G2F * 4) {
        const u16* arow = aggb + (size_t)(tile * 16 + m) * C_H + quad * 8;
        bf16x8 a0 = *(const bf16x8*)(arow);
        bf16x8 a1 = *(const bf16x8*)(arow + 32);
#pragma unroll
        for (int nt = 0; nt < 8; ++nt) {
            f32x4 acc = {0.f, 0.f, 0.f, 0.f};
            acc = __builtin_amdgcn_mfma_f32_16x16x32_bf16(a0, b[0][nt], acc, 0, 0, 0);
            acc = __builtin_amdgcn_mfma_f32_16x16x32_bf16(a1, b[1][nt], acc, 0, 0, 0);
#pragma unroll
            for (int r = 0; r < 4; ++r)
                pacc[nt] += fmaxf(acc[r] + bias[nt], 0.f);
        }
    }
#pragma unroll
    for (int nt = 0; nt < 8; ++nt) psum[(w * 8 + nt) * 64 + lane] = pacc[nt];
    __syncthreads();
    if (t < 128) {
        int nt = t >> 4, m2 = t & 15;
        float s = 0.f;
#pragma unroll
        for (int ww = 0; ww < 4; ++ww)
#pragma unroll
            for (int q = 0; q < 4; ++q)
                s += psum[(ww * 8 + nt) * 64 + q * 16 + m2];
        partial[blockIdx.x * C_OUT + t] = s;   // ch = nt*16 + m2 = t
    }
}

// ---------- final: mean + FC -> 2 outputs (dtype per flag) ----------
__global__ __launch_bounds__(512) void k_final(const float* __restrict__ partial,
                                               const float* __restrict__ fcWc,
                                               const float* __restrict__ fcbc,
                                               void* __restrict__ out,
                                               const int* __restrict__ flags) {
    __shared__ float sm[512];
    __shared__ float red[256];
    int t = threadIdx.x;
    int f = t & 127, c = t >> 7;
    float s = 0.f;
    for (int b = c; b < G2F; b += 4) s += partial[b * 128 + f];
    sm[t] = s;
    __syncthreads();
    if (t < 128) {
        float gm = (sm[t] + sm[t + 128] + sm[t + 256] + sm[t + 384]) * (1.0f / (float)N_NODES);
        red[t] = gm * fcWc[t];
        red[128 + t] = gm * fcWc[128 + t];
    }
    __syncthreads();
    for (int off = 64; off >= 1; off >>= 1) {
        if (t < off) {
            red[t] += red[t + off];
            red[128 + t] += red[128 + t + off];
        }
        __syncthreads();
    }
    if (t == 0) {
        float o0 = red[0] + fcbc[0];
        float o1 = red[128] + fcbc[1];
        if (flags[0]) {
            u16* ob = (u16*)out;
            ob[0] = f2bf(o0);
            ob[1] = f2bf(o1);
        } else {
            float* of = (float*)out;
            of[0] = o0;
            of[1] = o1;
        }
    }
}

// ---------- workspace layout (bytes) ----------
// csr int[E + NB*256 + pad] (self-loops + 64-entry overrun pad) = 13,200,384 B.
// agg (bf16, 12.8MB) aliases ebuf u32[E] (12.8MB): ebuf's last read (k_scatter2)
// precedes agg's first write (k_gatherM<1>) in stream order.
#define OFF_FLAGS   0u
#define OFF_DINV    512u         // float[N]
#define OFF_ROWPTR  400896u      // int[N+1]
#define OFF_BCNT    801280u      // u32[NB]
#define OFF_BBASE   802944u      // u32[NB+1]
#define OFF_BCUR    804608u      // u32[NB]
#define OFF_CSR     1201664u     // int[3300096]
#define OFF_H1      14402560u    // bf16[N*64]  (g1 = dinv*h1)
#define OFF_A1      27202560u    // bf16[N*64]  (a1s = dinv*relu(conv1))
#define OFF_AGG     40002560u    // bf16[N*64] (12.8MB) / ebuf u32[E] (12.8MB)
#define OFF_PART    52802560u    // float[G2F*128]
#define OFF_W1C     53122560u    // u16[256*64] (MFMA frag order)
#define OFF_W2C     53155328u    // u16[64*128] (MFMA frag order)
#define OFF_B1C     53171712u    // float[64]
#define OFF_B2C     53171968u    // float[128]
#define OFF_FCWC    53172480u    // float[256]
#define OFF_FCBC    53173504u    // float[2]

extern "C" void kernel_launch(void* const* d_in, const int* in_sizes, int n_in,
                              void* d_out, int out_size, void* d_ws, size_t ws_size,
                              hipStream_t stream) {
    (void)in_sizes; (void)n_in; (void)out_size; (void)ws_size;
    const void* x   = d_in[0];
    const int*  ei  = (const int*)d_in[1];
    const void* W1  = d_in[2];
    const void* b1  = d_in[3];
    const void* W2  = d_in[4];
    const void* b2  = d_in[5];
    const void* fcW = d_in[6];
    const void* fcb = d_in[7];

    char* ws = (char*)d_ws;
    int*   flags  = (int*)(ws + OFF_FLAGS);
    float* dinv   = (float*)(ws + OFF_DINV);
    int*   rowptr = (int*)(ws + OFF_ROWPTR);
    u32*   bcnt   = (u32*)(ws + OFF_BCNT);
    u32*   bbase  = (u32*)(ws + OFF_BBASE);
    u32*   bcur   = (u32*)(ws + OFF_BCUR);
    int*   csr    = (int*)(ws + OFF_CSR);
    u16*   g1     = (u16*)(ws + OFF_H1);
    u16*   a1s    = (u16*)(ws + OFF_A1);
    u16*   aggb   = (u16*)(ws + OFF_AGG);
    u32*   ebuf   = (u32*)(ws + OFF_AGG);
    float* partial= (float*)(ws + OFF_PART);
    u16*   W1m    = (u16*)(ws + OFF_W1C);
    u16*   W2m    = (u16*)(ws + OFF_W2C);
    float* b1c    = (float*)(ws + OFF_B1C);
    float* b2c    = (float*)(ws + OFF_B2C);
    float* fcWc   = (float*)(ws + OFF_FCWC);
    float* fcbc   = (float*)(ws + OFF_FCBC);

    k_detect<<<1, 256, 0, stream>>>(x, ei, b1, b2, fcW, fcb,
                                    flags, b1c, b2c, fcWc, fcbc);
    k_prep<<<96, 256, 0, stream>>>(W1, W2, flags, W1m, W2m, bcnt);
    k_hist1<<<NB, 256, 0, stream>>>(ei, flags, bcnt);
    k_bscan<<<1, 512, 0, stream>>>(bcnt, bbase, bcur, rowptr);
    k_scatter1<<<NB, 512, 0, stream>>>(ei, flags, bcur, ebuf);
    k_scatter2<<<NB, 256, 0, stream>>>(bbase, ebuf, rowptr, dinv, csr);
    k_gemm1<<<(N_NODES + 127) / 128, 256, 0, stream>>>(x, W1m, dinv, g1, flags);
    k_gatherM<0><<<G_GM, 256, 0, stream>>>(rowptr, csr, dinv, g1, b1c, a1s);
    k_gatherM<1><<<G_GM, 256, 0, stream>>>(rowptr, csr, dinv, a1s, b2c, aggb);
    k_fused2<<<G2F, 256, 0, stream>>>(aggb, W2m, b2c, partial);
    k_final<<<1, 512, 0, stream>>>(partial, fcWc, fcbc, (void*)d_out, flags);
}

// Round 4
// 388.109 us; speedup vs baseline: 1.0535x; 1.0535x over previous
//
#include <hip/hip_runtime.h>

#define N_NODES 100000
#define N_EDGES 3200000
#define C_IN 256
#define C_H 64
#define C_OUT 128
#define NB 391       // ceil(N_NODES/256) buckets of 256 nodes
#define BCAP 16384   // fixed per-bucket capacity in ebuf (mean 8184, 2x headroom)
#define G2F 625      // blocks for fused gemm2+pool
#define NTILES 6250  // N_NODES/16
#define NT16 6250    // gather tiles of 16 nodes
#define G_GM 1563    // ceil(NT16/4)
#define CH1 8192     // edges per block in scatter1

typedef unsigned int u32;
typedef unsigned short u16;
typedef unsigned long long u64;
typedef __attribute__((ext_vector_type(8))) short bf16x8;
typedef __attribute__((ext_vector_type(4))) float f32x4;

typedef __attribute__((address_space(3))) unsigned int l_u32;
typedef __attribute__((address_space(1))) const unsigned int g_u32;

// ---------- bf16 helpers ----------
__device__ __forceinline__ float bf2f(u16 u) {
    union { u32 i; float f; } v; v.i = ((u32)u) << 16; return v.f;
}
__device__ __forceinline__ u16 f2bf(float f) {
    union { float f; u32 i; } v; v.f = f;
    u32 x = v.i;
    return (u16)((x + 0x7fffu + ((x >> 16) & 1u)) >> 16);  // RNE
}

__device__ __forceinline__ void gll16(const void* gp, const u16* lp) {
    __builtin_amdgcn_global_load_lds((g_u32*)gp, (l_u32*)lp, 16, 0, 0);
}

// ---------- slim detection: flags + small tensors ----------
__global__ void k_detect(const void* __restrict__ x, const void* __restrict__ ei,
                         const void* __restrict__ b1, const void* __restrict__ b2,
                         const void* __restrict__ fcW, const void* __restrict__ fcb,
                         int* __restrict__ flags,
                         float* __restrict__ b1c, float* __restrict__ b2c,
                         float* __restrict__ fcWc, float* __restrict__ fcbc) {
    __shared__ int sf[2];
    int t = threadIdx.x;
    if (t < 64) {
        u32 w = ((const u32*)x)[t];
        u32 low = w & 0xffffu;
        int e = (int)((low >> 7) & 0xff);
        bool inw = (e > 96 && e < 160) || (low == 0);
        u64 m = __ballot(inw);
        if (t == 0) sf[0] = (__popcll(m) >= 60) ? 1 : 0;
    } else if (t < 128) {
        int i = t - 64;
        u32 w = ((const u32*)ei)[2 * i + 1];
        u64 m = __ballot(w == 0);
        if (i == 0) sf[1] = (m == ~0ull) ? 1 : 0;
    }
    __syncthreads();
    if (t == 0) { flags[0] = sf[0]; flags[1] = sf[1]; }
    int isbf = sf[0];
    if (isbf) {
        const u16* p1 = (const u16*)b1;  const u16* p2 = (const u16*)b2;
        const u16* pw = (const u16*)fcW; const u16* pb = (const u16*)fcb;
        for (int i = t; i < C_H; i += 256) b1c[i] = bf2f(p1[i]);
        for (int i = t; i < C_OUT; i += 256) b2c[i] = bf2f(p2[i]);
        for (int i = t; i < 2 * C_OUT; i += 256) fcWc[i] = bf2f(pw[i]);
        for (int i = t; i < 2; i += 256) fcbc[i] = bf2f(pb[i]);
    } else {
        const float* p1 = (const float*)b1;  const float* p2 = (const float*)b2;
        const float* pw = (const float*)fcW; const float* pb = (const float*)fcb;
        for (int i = t; i < C_H; i += 256) b1c[i] = p1[i];
        for (int i = t; i < C_OUT; i += 256) b2c[i] = p2[i];
        for (int i = t; i < 2 * C_OUT; i += 256) fcWc[i] = pw[i];
        for (int i = t; i < 2; i += 256) fcbc[i] = pb[i];
    }
}

// ---------- parallel prep: W1m/W2m frag-order swizzles + bucket_cnt zero ----------
__global__ __launch_bounds__(256) void k_prep(const void* __restrict__ W1,
                                              const void* __restrict__ W2,
                                              const int* __restrict__ flags,
                                              u16* __restrict__ W1m, u16* __restrict__ W2m,
                                              u32* __restrict__ bucket_cnt) {
    int b = blockIdx.x, t = threadIdx.x;
    int isbf = flags[0];
    int i = b * 256 + t;
    if (i < NB) bucket_cnt[i] = 0;
    if (i < C_IN * C_H) {
        const u16* w1b = (const u16*)W1; const float* w1f = (const float*)W1;
        int j = i & 7, lane = (i >> 3) & 63, nt = (i >> 9) & 3, k0 = i >> 11;
        int k = k0 * 32 + ((lane >> 4) & 3) * 8 + j;
        int n = nt * 16 + (lane & 15);
        W1m[i] = isbf ? w1b[k * C_H + n] : f2bf(w1f[k * C_H + n]);
    } else {
        int i2 = i - C_IN * C_H;
        const u16* w2b = (const u16*)W2; const float* w2f = (const float*)W2;
        int j = i2 & 7, lane = (i2 >> 3) & 63, nt = (i2 >> 9) & 7, k0 = (i2 >> 12) & 1;
        int k = k0 * 32 + ((lane >> 4) & 3) * 8 + j;
        int n = nt * 16 + (lane & 15);
        W2m[i2] = isbf ? w2b[k * C_OUT + n] : f2bf(w2f[k * C_OUT + n]);
    }
}

// ---------- pass 1: bucket-sorted staged scatter into fixed-capacity buckets ----------
// bucket_cnt doubles as the allocation cursor (starts 0, ends = count).
__global__ __launch_bounds__(512) void k_scatter1(const int* __restrict__ ei,
                                                  const int* __restrict__ flags,
                                                  u32* __restrict__ bucket_cnt,
                                                  u32* __restrict__ ebuf) {
    __shared__ u32 cnt[NB];
    __shared__ u32 lcur[NB];
    __shared__ u32 gbase[NB];
    __shared__ u32 lofs[512];
    __shared__ u32 stp[CH1];
    __shared__ u16 stb[CH1];
    int t = threadIdx.x;
    int is64 = flags[1];
    int e0 = blockIdx.x * CH1;
    int nv = min(CH1, N_EDGES - e0);
    for (int i = t; i < NB; i += 512) { cnt[i] = 0; lcur[i] = 0; }
    __syncthreads();
    for (int i = t; i < nv; i += 512) {
        int e = e0 + i;
        int d = is64 ? ei[2 * (N_EDGES + e)] : ei[N_EDGES + e];
        atomicAdd(&cnt[d >> 8], 1u);
    }
    __syncthreads();
    u32 v = (t < NB) ? cnt[t] : 0;
    lofs[t] = v;
    __syncthreads();
    for (int off = 1; off < 512; off <<= 1) {
        u32 a = (t >= off) ? lofs[t - off] : 0;
        __syncthreads();
        lofs[t] += a;
        __syncthreads();
    }
    u32 excl = lofs[t] - v;
    __syncthreads();
    lofs[t] = excl;
    __syncthreads();
    for (int i = t; i < nv; i += 512) {
        int e = e0 + i;
        int d, s;
        if (is64) { d = ei[2 * (N_EDGES + e)]; s = ei[2 * e]; }
        else      { d = ei[N_EDGES + e];       s = ei[e]; }
        int b = d >> 8;
        u32 slot = lofs[b] + atomicAdd(&lcur[b], 1u);
        stp[slot] = ((u32)(d & 255) << 20) | (u32)s;
        stb[slot] = (u16)b;
    }
    __syncthreads();
    for (int b = t; b < NB; b += 512) {
        u32 c = cnt[b];
        gbase[b] = c ? atomicAdd(&bucket_cnt[b], c) : 0;
    }
    __syncthreads();
    for (int s = t; s < nv; s += 512) {
        int b = stb[s];
        ebuf[(size_t)b * BCAP + gbase[b] + (s - lofs[b])] = stp[s];
    }
}

// ---------- scan bucket counts -> dense csr bases ----------
__global__ __launch_bounds__(512) void k_bscan(const u32* __restrict__ bucket_cnt,
                                               u32* __restrict__ bucket_base) {
    __shared__ u32 sm[512];
    int t = threadIdx.x;
    u32 v = (t < NB) ? bucket_cnt[t] : 0;
    sm[t] = v;
    __syncthreads();
    for (int off = 1; off < 512; off <<= 1) {
        u32 a = (t >= off) ? sm[t - off] : 0;
        __syncthreads();
        sm[t] += a;
        __syncthreads();
    }
    if (t < NB) bucket_base[t] = sm[t] - v;
    if (t == 0) bucket_base[NB] = N_EDGES;
}

// ---------- pass 2: per-bucket local sort -> csr (byte offsets, WITH self-loops) ----------
// csr row for node n: [rowptr[n], rowptr[n+1]) ; first entry = self (n*128),
// then the in-edges' src byte offsets (src*128). rowptr[N] set by last node.
__global__ __launch_bounds__(256) void k_scatter2(const u32* __restrict__ bucket_base,
                                                  const u32* __restrict__ ebuf,
                                                  int* __restrict__ rowptr,
                                                  float* __restrict__ dinv,
                                                  int* __restrict__ csr) {
    __shared__ int cnt[256];
    __shared__ int pfx[256];
    __shared__ int lcur[256];
    int b = blockIdx.x, t = threadIdx.x;
    int ebeg = (int)bucket_base[b], eend = (int)bucket_base[b + 1];
    int ne = eend - ebeg;
    const u32* src = ebuf + (size_t)b * BCAP;
    int sbeg = ebeg + (b << 8);   // +1 self slot per node in prior (full) buckets
    cnt[t] = 0;
    lcur[t] = 0;
    __syncthreads();
    for (int i = t; i < ne; i += 256)
        atomicAdd(&cnt[(src[i] >> 20) & 255], 1);
    __syncthreads();
    int v = cnt[t];
    pfx[t] = v;
    __syncthreads();
    for (int off = 1; off < 256; off <<= 1) {
        int a = (t >= off) ? pfx[t - off] : 0;
        __syncthreads();
        pfx[t] += a;
        __syncthreads();
    }
    int node = (b << 8) + t;
    int rstart = sbeg + (pfx[t] - v) + t;
    if (node < N_NODES) {
        rowptr[node] = rstart;
        dinv[node] = rsqrtf((float)(v + 1));
        csr[rstart] = node << 7;            // self-loop, byte offset
        if (node == N_NODES - 1) {
            rowptr[N_NODES] = rstart + v + 1;
            for (int i = 0; i < 64; ++i) csr[rstart + v + 1 + i] = 0;  // chunk-overrun pad
        }
    }
    __syncthreads();
    for (int i = t; i < ne; i += 256) {
        u32 p = src[i];
        int dl = (p >> 20) & 255;
        int pos = sbeg + (pfx[dl] - cnt[dl]) + dl + 1 + atomicAdd(&lcur[dl], 1);
        csr[pos] = (int)((p & 0x1FFFFu) << 7);   // src byte offset
    }
}

// ---------- MFMA GEMM1: g1[N,64] = dinv ⊙ (x[N,256] @ W1[256,64]) ----------
__global__ __launch_bounds__(256) void k_gemm1(const void* __restrict__ xv,
                                               const u16* __restrict__ W1m,
                                               const float* __restrict__ dinv,
                                               u16* __restrict__ g1,
                                               const int* __restrict__ flags) {
    __shared__ u16 wlds[C_IN * C_H];   // 32 KB
    int t = threadIdx.x;
    int isbf = flags[0];
    {
        const uint4* src = (const uint4*)W1m;
        uint4* dst = (uint4*)wlds;
#pragma unroll
        for (int it = 0; it < 8; ++it) dst[t + it * 256] = src[t + it * 256];
    }
    __syncthreads();
    int w = t >> 6, lane = t & 63;
    int quad = lane >> 4, mrow = lane & 15;
    int m0 = blockIdx.x * 128 + w * 32;
    if (m0 >= N_NODES) return;

    bf16x8 a[2][8];
    if (isbf) {
        const u16* xb = (const u16*)xv;
#pragma unroll
        for (int mt = 0; mt < 2; ++mt)
#pragma unroll
            for (int k0 = 0; k0 < 8; ++k0)
                a[mt][k0] = *(const bf16x8*)(xb + (size_t)(m0 + mt * 16 + mrow) * C_IN + k0 * 32 + quad * 8);
    } else {
        const float* xf = (const float*)xv;
#pragma unroll
        for (int mt = 0; mt < 2; ++mt)
#pragma unroll
            for (int k0 = 0; k0 < 8; ++k0) {
                const float* p = xf + (size_t)(m0 + mt * 16 + mrow) * C_IN + k0 * 32 + quad * 8;
                float4 v0 = *(const float4*)p;
                float4 v1 = *(const float4*)(p + 4);
                bf16x8 r;
                r[0] = (short)f2bf(v0.x); r[1] = (short)f2bf(v0.y);
                r[2] = (short)f2bf(v0.z); r[3] = (short)f2bf(v0.w);
                r[4] = (short)f2bf(v1.x); r[5] = (short)f2bf(v1.y);
                r[6] = (short)f2bf(v1.z); r[7] = (short)f2bf(v1.w);
                a[mt][k0] = r;
            }
    }

    float dv0[4], dv1[4];
#pragma unroll
    for (int r = 0; r < 4; ++r) {
        dv0[r] = dinv[m0 + quad * 4 + r];
        dv1[r] = dinv[m0 + 16 + quad * 4 + r];
    }

#pragma unroll
    for (int nt = 0; nt < 4; ++nt) {
        bf16x8 b[8];
#pragma unroll
        for (int k0 = 0; k0 < 8; ++k0)
            b[k0] = *(const bf16x8*)&wlds[((k0 * 4 + nt) * 64 + lane) * 8];
        f32x4 acc0 = {0.f, 0.f, 0.f, 0.f};
        f32x4 acc1 = {0.f, 0.f, 0.f, 0.f};
#pragma unroll
        for (int k0 = 0; k0 < 8; ++k0) {
            acc0 = __builtin_amdgcn_mfma_f32_16x16x32_bf16(a[0][k0], b[k0], acc0, 0, 0, 0);
            acc1 = __builtin_amdgcn_mfma_f32_16x16x32_bf16(a[1][k0], b[k0], acc1, 0, 0, 0);
        }
        int ch = nt * 16 + mrow;   // D: col = lane&15
#pragma unroll
        for (int r = 0; r < 4; ++r) {   // D: row = quad*4 + r
            g1[(size_t)(m0 + quad * 4 + r) * C_H + ch] = f2bf(acc0[r] * dv0[r]);
            g1[(size_t)(m0 + 16 + quad * 4 + r) * C_H + ch] = f2bf(acc1[r] * dv1[r]);
        }
    }
}

// ---------- MFMA gather: out[16-node tile] = Sel(32 edges) x G(32 rows), chunked ----------
// One wave per 16-node tile. CSR (dst-sorted, self-loops included) streamed in
// 32-edge chunks. Staging (call it, lane l): edge E = it*8+(l>>3), channel octet
// l&7 -> LDS byte (E>>3)*1024 + (E&7)*128 + (ch>>3)*16 + (ch&7)*2. Fragments
// assembled with plain ds_read_u16 (deterministic). A = 0/1 run selector LUT.
// MODE 0: out = bf16(dinv * relu(dinv*sum + bias))   MODE 1: out = bf16(dinv*sum)
template <int MODE>
__global__ __launch_bounds__(256) void k_gatherM(const int* __restrict__ rowptr,
                                                 const int* __restrict__ csrb,
                                                 const float* __restrict__ dinv,
                                                 const u16* __restrict__ gt,
                                                 const float* __restrict__ bias,
                                                 u16* __restrict__ out) {
    __shared__ __align__(16) u16 hs[4][4096];   // per wave: 2 buffers x 4KB
    __shared__ bf16x8 lut[81];                  // run patterns ones[s..e)
    int t = threadIdx.x;
    if (t < 81) {
        int s = t / 9, e = t - s * 9;
        bf16x8 le;
#pragma unroll
        for (int j = 0; j < 8; ++j) le[j] = (short)((j >= s && j < e) ? 0x3F80 : 0);
        lut[t] = le;
    }
    __syncthreads();
    int w = t >> 6, lane = t & 63;
    int tile = blockIdx.x * 4 + w;
    if (tile >= NT16) return;

    int g16 = lane >> 4, c = lane & 15;
    int n0 = tile << 4;
    int lo = rowptr[n0 + c];
    int hi = rowptr[n0 + c + 1];
    int beg = __shfl(lo, 0, 64);
    int end = __shfl(hi, 15, 64);
    int eidx = lane >> 3;            // edge-in-slice staged by this lane
    int boff = (lane & 7) * 16;      // byte offset (channel octet) within row
    const char* gb = (const char*)gt;
    f32x4 acc0 = {0.f, 0.f, 0.f, 0.f}, acc1 = acc0, acc2 = acc0, acc3 = acc0;
    int nch = (end - beg + 31) >> 5;
    int cb = beg;
    {   // prologue: stage chunk 0 into buffer 0
        u32 o0 = (u32)csrb[cb + eidx];
        u32 o1 = (u32)csrb[cb + 8 + eidx];
        u32 o2 = (u32)csrb[cb + 16 + eidx];
        u32 o3 = (u32)csrb[cb + 24 + eidx];
        gll16(gb + o0 + boff, &hs[w][0]);
        gll16(gb + o1 + boff, &hs[w][512]);
        gll16(gb + o2 + boff, &hs[w][1024]);
        gll16(gb + o3 + boff, &hs[w][1536]);
        asm volatile("" ::: "memory");   // pin: later loads can't hoist above glls
    }
    for (int ci = 0; ci < nch; ++ci) {
        int cbn = cb + 32;
        bool more = (ci + 1 < nch);
        u32 n0o = 0, n1o = 0, n2o = 0, n3o = 0;
        if (more) {                                   // issue next chunk's csr loads
            n0o = (u32)csrb[cbn + eidx];
            n1o = (u32)csrb[cbn + 8 + eidx];
            n2o = (u32)csrb[cbn + 16 + eidx];
            n3o = (u32)csrb[cbn + 24 + eidx];
        }
        if (more) asm volatile("s_waitcnt vmcnt(4)" ::: "memory");   // staging glls done
        else      asm volatile("s_waitcnt vmcnt(0)" ::: "memory");
        // fragment assembly: lane (c,g16), element (j,cht) at
        // buf + g16*1024 + j*128 + cht*32 + (c>>3)*16 + (c&7)*2   [bytes]
        const u16* lp = &hs[w][((ci & 1) << 11) + g16 * 512 + ((c >> 3) << 3) + (c & 7)];
        bf16x8 bfr[4];
#pragma unroll
        for (int cht = 0; cht < 4; ++cht) {
            u32 w0 = (u32)lp[0 * 64 + cht * 16] | ((u32)lp[1 * 64 + cht * 16] << 16);
            u32 w1 = (u32)lp[2 * 64 + cht * 16] | ((u32)lp[3 * 64 + cht * 16] << 16);
            u32 w2 = (u32)lp[4 * 64 + cht * 16] | ((u32)lp[5 * 64 + cht * 16] << 16);
            u32 w3 = (u32)lp[6 * 64 + cht * 16] | ((u32)lp[7 * 64 + cht * 16] << 16);
            union { u32 u[4]; bf16x8 v; } z;
            z.u[0] = w0; z.u[1] = w1; z.u[2] = w2; z.u[3] = w3;
            bfr[cht] = z.v;
        }
        int cbg = cb + g16 * 8;
        int s0 = min(max(lo - cbg, 0), 8);
        int e0 = min(max(hi - cbg, 0), 8);
        bf16x8 af = lut[s0 * 9 + e0];
        acc0 = __builtin_amdgcn_mfma_f32_16x16x32_bf16(af, bfr[0], acc0, 0, 0, 0);
        acc1 = __builtin_amdgcn_mfma_f32_16x16x32_bf16(af, bfr[1], acc1, 0, 0, 0);
        acc2 = __builtin_amdgcn_mfma_f32_16x16x32_bf16(af, bfr[2], acc2, 0, 0, 0);
        acc3 = __builtin_amdgcn_mfma_f32_16x16x32_bf16(af, bfr[3], acc3, 0, 0, 0);
        if (more) {                                   // stage next chunk, other buffer
            int bo = ((ci + 1) & 1) << 11;
            gll16(gb + n0o + boff, &hs[w][bo]);
            gll16(gb + n1o + boff, &hs[w][bo + 512]);
            gll16(gb + n2o + boff, &hs[w][bo + 1024]);
            gll16(gb + n3o + boff, &hs[w][bo + 1536]);
            asm volatile("" ::: "memory");   // pin: next iter's csr loads stay below
        }
        cb = cbn;
    }
    // epilogue: D row = node (lane>>4)*4+r, D col = channel cht*16 + (lane&15)
    float dv[4];
    int nb = n0 + g16 * 4;
#pragma unroll
    for (int r = 0; r < 4; ++r) dv[r] = dinv[nb + r];
    u16* ob = out + (size_t)nb * C_H + c;
#define EPI(ACC, CHT)                                                              \
    {                                                                              \
        float bs = (MODE == 0) ? bias[CHT * 16 + c] : 0.f;                         \
        _Pragma("unroll")                                                          \
        for (int r = 0; r < 4; ++r) {                                              \
            float val = (MODE == 0) ? dv[r] * fmaxf(dv[r] * ACC[r] + bs, 0.f)      \
                                    : dv[r] * ACC[r];                              \
            ob[r * C_H + CHT * 16] = f2bf(val);                                    \
        }                                                                          \
    }
    EPI(acc0, 0) EPI(acc1, 1) EPI(acc2, 2) EPI(acc3, 3)
#undef EPI
}

// ---------- fused MFMA GEMM2 + bias + relu + mean-pool partials ----------
__global__ __launch_bounds__(256) void k_fused2(const u16* __restrict__ aggb,
                                                const u16* __restrict__ W2m,
                                                const float* __restrict__ b2c,
                                                float* __restrict__ partial) {
    __shared__ float psum[4 * 8 * 64];   // [wave][nt][lane], 8 KB
    int t = threadIdx.x;
    int w = t >> 6, lane = t & 63;
    int quad = lane >> 4, m = lane & 15;

    bf16x8 b[2][8];
#pragma unroll
    for (int k0 = 0; k0 < 2; ++k0)
#pragma unroll
        for (int nt = 0; nt < 8; ++nt)
            b[k0][nt] = *(const bf16x8*)&W2m[((k0 * 8 + nt) * 64 + lane) * 8];

    float pacc[8] = {0.f, 0.f, 0.f, 0.f, 0.f, 0.f, 0.f, 0.f};
    float bias[8];
#pragma unroll
    for (int nt = 0; nt < 8; ++nt) bias[nt] = b2c[nt * 16 + m];

    for (int tile = blockIdx.x * 4 + w; tile < NTILES; tile += G2F * 4) {
        const u16* arow = aggb + (size_t)(tile * 16 + m) * C_H + quad * 8;
        bf16x8 a0 = *(const bf16x8*)(arow);
        bf16x8 a1 = *(const bf16x8*)(arow + 32);
#pragma unroll
        for (int nt = 0; nt < 8; ++nt) {
            f32x4 acc = {0.f, 0.f, 0.f, 0.f};
            acc = __builtin_amdgcn_mfma_f32_16x16x32_bf16(a0, b[0][nt], acc, 0, 0, 0);
            acc = __builtin_amdgcn_mfma_f32_16x16x32_bf16(a1, b[1][nt], acc, 0, 0, 0);
#pragma unroll
            for (int r = 0; r < 4; ++r)
                pacc[nt] += fmaxf(acc[r] + bias[nt], 0.f);
        }
    }
#pragma unroll
    for (int nt = 0; nt < 8; ++nt) psum[(w * 8 + nt) * 64 + lane] = pacc[nt];
    __syncthreads();
    if (t < 128) {
        int nt = t >> 4, m2 = t & 15;
        float s = 0.f;
#pragma unroll
        for (int ww = 0; ww < 4; ++ww)
#pragma unroll
            for (int q = 0; q < 4; ++q)
                s += psum[(ww * 8 + nt) * 64 + q * 16 + m2];
        partial[blockIdx.x * C_OUT + t] = s;   // ch = nt*16 + m2 = t
    }
}

// ---------- final: mean + FC -> 2 outputs (dtype per flag) ----------
__global__ __launch_bounds__(512) void k_final(const float* __restrict__ partial,
                                               const float* __restrict__ fcWc,
                                               const float* __restrict__ fcbc,
                                               void* __restrict__ out,
                                               const int* __restrict__ flags) {
    __shared__ float sm[512];
    __shared__ float red[256];
    int t = threadIdx.x;
    int f = t & 127, c = t >> 7;
    float s = 0.f;
    for (int b = c; b < G2F; b += 4) s += partial[b * 128 + f];
    sm[t] = s;
    __syncthreads();
    if (t < 128) {
        float gm = (sm[t] + sm[t + 128] + sm[t + 256] + sm[t + 384]) * (1.0f / (float)N_NODES);
        red[t] = gm * fcWc[t];
        red[128 + t] = gm * fcWc[128 + t];
    }
    __syncthreads();
    for (int off = 64; off >= 1; off >>= 1) {
        if (t < off) {
            red[t] += red[t + off];
            red[128 + t] += red[128 + t + off];
        }
        __syncthreads();
    }
    if (t == 0) {
        float o0 = red[0] + fcbc[0];
        float o1 = red[128] + fcbc[1];
        if (flags[0]) {
            u16* ob = (u16*)out;
            ob[0] = f2bf(o0);
            ob[1] = f2bf(o1);
        } else {
            float* of = (float*)out;
            of[0] = o0;
            of[1] = o1;
        }
    }
}

// ---------- workspace layout (bytes) ----------
// csr int[E + NB*256 + pad] (self-loops + 64-entry overrun pad) = 13,200,384 B.
// ebuf now a DEDICATED u32[NB*BCAP] region (25.6MB) — fixed-capacity buckets,
// no hist pre-pass. ws is ~400MB (per harness poison fill), usage tops at ~92MB.
#define OFF_FLAGS   0u
#define OFF_DINV    512u         // float[N]
#define OFF_ROWPTR  400896u      // int[N+1]
#define OFF_BCNT    801280u      // u32[NB]
#define OFF_BBASE   802944u      // u32[NB+1]
#define OFF_CSR     1201664u     // int[3300096]
#define OFF_H1      14402560u    // bf16[N*64]  (g1 = dinv*h1)
#define OFF_A1      27202560u    // bf16[N*64]  (a1s = dinv*relu(conv1))
#define OFF_AGG     40002560u    // bf16[N*64]
#define OFF_PART    52802560u    // float[G2F*128]
#define OFF_W1C     53122560u    // u16[256*64] (MFMA frag order)
#define OFF_W2C     53155328u    // u16[64*128] (MFMA frag order)
#define OFF_B1C     53171712u    // float[64]
#define OFF_B2C     53171968u    // float[128]
#define OFF_FCWC    53172480u    // float[256]
#define OFF_FCBC    53173504u    // float[2]
#define OFF_EBUF    53174272u    // u32[NB*BCAP] = 25,624,576 B (ends ~78.8MB)

extern "C" void kernel_launch(void* const* d_in, const int* in_sizes, int n_in,
                              void* d_out, int out_size, void* d_ws, size_t ws_size,
                              hipStream_t stream) {
    (void)in_sizes; (void)n_in; (void)out_size; (void)ws_size;
    const void* x   = d_in[0];
    const int*  ei  = (const int*)d_in[1];
    const void* W1  = d_in[2];
    const void* b1  = d_in[3];
    const void* W2  = d_in[4];
    const void* b2  = d_in[5];
    const void* fcW = d_in[6];
    const void* fcb = d_in[7];

    char* ws = (char*)d_ws;
    int*   flags  = (int*)(ws + OFF_FLAGS);
    float* dinv   = (float*)(ws + OFF_DINV);
    int*   rowptr = (int*)(ws + OFF_ROWPTR);
    u32*   bcnt   = (u32*)(ws + OFF_BCNT);
    u32*   bbase  = (u32*)(ws + OFF_BBASE);
    int*   csr    = (int*)(ws + OFF_CSR);
    u16*   g1     = (u16*)(ws + OFF_H1);
    u16*   a1s    = (u16*)(ws + OFF_A1);
    u16*   aggb   = (u16*)(ws + OFF_AGG);
    u32*   ebuf   = (u32*)(ws + OFF_EBUF);
    float* partial= (float*)(ws + OFF_PART);
    u16*   W1m    = (u16*)(ws + OFF_W1C);
    u16*   W2m    = (u16*)(ws + OFF_W2C);
    float* b1c    = (float*)(ws + OFF_B1C);
    float* b2c    = (float*)(ws + OFF_B2C);
    float* fcWc   = (float*)(ws + OFF_FCWC);
    float* fcbc   = (float*)(ws + OFF_FCBC);

    k_detect<<<1, 256, 0, stream>>>(x, ei, b1, b2, fcW, fcb,
                                    flags, b1c, b2c, fcWc, fcbc);
    k_prep<<<96, 256, 0, stream>>>(W1, W2, flags, W1m, W2m, bcnt);
    k_scatter1<<<NB, 512, 0, stream>>>(ei, flags, bcnt, ebuf);
    k_bscan<<<1, 512, 0, stream>>>(bcnt, bbase);
    k_scatter2<<<NB, 256, 0, stream>>>(bbase, ebuf, rowptr, dinv, csr);
    k_gemm1<<<(N_NODES + 127) / 128, 256, 0, stream>>>(x, W1m, dinv, g1, flags);
    k_gatherM<0><<<G_GM, 256, 0, stream>>>(rowptr, csr, dinv, g1, b1c, a1s);
    k_gatherM<1><<<G_GM, 256, 0, stream>>>(rowptr, csr, dinv, a1s, b2c, aggb);
    k_fused2<<<G2F, 256, 0, stream>>>(aggb, W2m, b2c, partial);
    k_final<<<1, 512, 0, stream>>>(partial, fcWc, fcbc, (void*)d_out, flags);
}

// Round 5
// 361.308 us; speedup vs baseline: 1.1316x; 1.0742x over previous
//
#include <hip/hip_runtime.h>

#define N_NODES 100000
#define N_EDGES 3200000
#define C_IN 256
#define C_H 64
#define C_OUT 128
#define NB 391       // ceil(N_NODES/256) buckets of 256 nodes
#define BCAP 16384   // fixed per-bucket capacity in ebuf (mean 8184, 2x headroom)
#define G2F 625      // blocks for fused gemm2+pool
#define NTILES 6250  // N_NODES/16
#define NT16 6250    // gather tiles of 16 nodes
#define G_GM 1563    // ceil(NT16/4)
#define CH1 8192     // edges per block in scatter1

typedef unsigned int u32;
typedef unsigned short u16;
typedef unsigned char u8;
typedef unsigned long long u64;
typedef __attribute__((ext_vector_type(8))) short bf16x8;
typedef __attribute__((ext_vector_type(4))) float f32x4;

typedef __attribute__((address_space(3))) unsigned int l_u32;
typedef __attribute__((address_space(1))) const unsigned int g_u32;

// ---------- bf16 / fp8 helpers ----------
__device__ __forceinline__ float bf2f(u16 u) {
    union { u32 i; float f; } v; v.i = ((u32)u) << 16; return v.f;
}
__device__ __forceinline__ u16 f2bf(float f) {
    union { float f; u32 i; } v; v.f = f;
    u32 x = v.i;
    return (u16)((x + 0x7fffu + ((x >> 16) & 1u)) >> 16);  // RNE
}
// f32 -> OCP e4m3fn, RNE, saturate to 448
__device__ __forceinline__ u8 f2fp8(float f) {
    union { float f; u32 i; } v; v.f = f;
    u32 s = (v.i >> 24) & 0x80u;
    float a = __builtin_fabsf(f);
    a = fminf(a, 448.f);
    if (a < 0.015625f) {                              // subnormal region, step 2^-9
        int m = (int)__builtin_rintf(a * 512.f);      // 0..8 (8 carries to 2^-6)
        return (u8)(s | (u32)m);
    }
    union { float ff; u32 i; } w; w.ff = a;
    u32 x = w.i;
    u32 r = x + 0x7FFFFu + ((x >> 20) & 1u);          // RNE into 3-bit mantissa
    u32 E = (r >> 23) - 120u;                         // 1..15
    u32 m = (r >> 20) & 7u;
    return (u8)(s | (E << 3) | m);
}

__device__ __forceinline__ void gll16(const void* gp, const void* lp) {
    __builtin_amdgcn_global_load_lds((g_u32*)gp, (l_u32*)lp, 16, 0, 0);
}

// ---------- prep: detect flags + small-tensor conversions + W swizzles + bcnt zero ----------
__global__ __launch_bounds__(256) void k_prep(const void* __restrict__ x, const void* __restrict__ ei,
                                              const void* __restrict__ W1, const void* __restrict__ W2,
                                              const void* __restrict__ b1, const void* __restrict__ b2,
                                              const void* __restrict__ fcW, const void* __restrict__ fcb,
                                              int* __restrict__ flags,
                                              u16* __restrict__ W1m, u16* __restrict__ W2m,
                                              u32* __restrict__ bucket_cnt,
                                              float* __restrict__ b1c, float* __restrict__ b2c,
                                              float* __restrict__ fcWc, float* __restrict__ fcbc) {
    __shared__ int sfb;
    int b = blockIdx.x, t = threadIdx.x;
    if (t < 64) {
        u32 wv = ((const u32*)x)[t];
        u32 low = wv & 0xffffu;
        int e = (int)((low >> 7) & 0xff);
        bool inw = (e > 96 && e < 160) || (low == 0);
        u64 m = __ballot(inw);
        if (t == 0) sfb = (__popcll(m) >= 60) ? 1 : 0;
    } else if (b == 0 && t < 128) {
        int i = t - 64;
        u32 wv = ((const u32*)ei)[2 * i + 1];
        u64 m = __ballot(wv == 0);
        if (i == 0) flags[1] = (m == ~0ull) ? 1 : 0;
    }
    __syncthreads();
    int isbf = sfb;
    if (b == 0 && t == 0) flags[0] = isbf;
    int i = b * 256 + t;
    if (i < NB) bucket_cnt[i] = 0;
    if (i < C_IN * C_H) {
        const u16* w1b = (const u16*)W1; const float* w1f = (const float*)W1;
        int j = i & 7, lane = (i >> 3) & 63, nt = (i >> 9) & 3, k0 = i >> 11;
        int k = k0 * 32 + ((lane >> 4) & 3) * 8 + j;
        int n = nt * 16 + (lane & 15);
        W1m[i] = isbf ? w1b[k * C_H + n] : f2bf(w1f[k * C_H + n]);
    } else {
        int i2 = i - C_IN * C_H;
        const u16* w2b = (const u16*)W2; const float* w2f = (const float*)W2;
        int j = i2 & 7, lane = (i2 >> 3) & 63, nt = (i2 >> 9) & 7, k0 = (i2 >> 12) & 1;
        int k = k0 * 32 + ((lane >> 4) & 3) * 8 + j;
        int n = nt * 16 + (lane & 15);
        W2m[i2] = isbf ? w2b[k * C_OUT + n] : f2bf(w2f[k * C_OUT + n]);
    }
    if (b == 0) {
        if (isbf) {
            const u16* p1 = (const u16*)b1;  const u16* p2 = (const u16*)b2;
            const u16* pw = (const u16*)fcW; const u16* pb = (const u16*)fcb;
            for (int q = t; q < C_H; q += 256) b1c[q] = bf2f(p1[q]);
            for (int q = t; q < C_OUT; q += 256) b2c[q] = bf2f(p2[q]);
            for (int q = t; q < 2 * C_OUT; q += 256) fcWc[q] = bf2f(pw[q]);
            for (int q = t; q < 2; q += 256) fcbc[q] = bf2f(pb[q]);
        } else {
            const float* p1 = (const float*)b1;  const float* p2 = (const float*)b2;
            const float* pw = (const float*)fcW; const float* pb = (const float*)fcb;
            for (int q = t; q < C_H; q += 256) b1c[q] = p1[q];
            for (int q = t; q < C_OUT; q += 256) b2c[q] = p2[q];
            for (int q = t; q < 2 * C_OUT; q += 256) fcWc[q] = pw[q];
            for (int q = t; q < 2; q += 256) fcbc[q] = pb[q];
        }
    }
}

// ---------- pass 1: bucket-sorted staged scatter into fixed-capacity buckets ----------
// bucket_cnt doubles as the allocation cursor (starts 0, ends = count).
__global__ __launch_bounds__(512) void k_scatter1(const int* __restrict__ ei,
                                                  const int* __restrict__ flags,
                                                  u32* __restrict__ bucket_cnt,
                                                  u32* __restrict__ ebuf) {
    __shared__ u32 cnt[NB];
    __shared__ u32 lcur[NB];
    __shared__ u32 gbase[NB];
    __shared__ u32 lofs[512];
    __shared__ u32 stp[CH1];
    __shared__ u16 stb[CH1];
    int t = threadIdx.x;
    int is64 = flags[1];
    int e0 = blockIdx.x * CH1;
    int nv = min(CH1, N_EDGES - e0);
    for (int i = t; i < NB; i += 512) { cnt[i] = 0; lcur[i] = 0; }
    __syncthreads();
    for (int i = t; i < nv; i += 512) {
        int e = e0 + i;
        int d = is64 ? ei[2 * (N_EDGES + e)] : ei[N_EDGES + e];
        atomicAdd(&cnt[d >> 8], 1u);
    }
    __syncthreads();
    u32 v = (t < NB) ? cnt[t] : 0;
    lofs[t] = v;
    __syncthreads();
    for (int off = 1; off < 512; off <<= 1) {
        u32 a = (t >= off) ? lofs[t - off] : 0;
        __syncthreads();
        lofs[t] += a;
        __syncthreads();
    }
    u32 excl = lofs[t] - v;
    __syncthreads();
    lofs[t] = excl;
    __syncthreads();
    for (int i = t; i < nv; i += 512) {
        int e = e0 + i;
        int d, s;
        if (is64) { d = ei[2 * (N_EDGES + e)]; s = ei[2 * e]; }
        else      { d = ei[N_EDGES + e];       s = ei[e]; }
        int b = d >> 8;
        u32 slot = lofs[b] + atomicAdd(&lcur[b], 1u);
        stp[slot] = ((u32)(d & 255) << 20) | (u32)s;
        stb[slot] = (u16)b;
    }
    __syncthreads();
    for (int b = t; b < NB; b += 512) {
        u32 c = cnt[b];
        gbase[b] = c ? atomicAdd(&bucket_cnt[b], c) : 0;
    }
    __syncthreads();
    for (int s = t; s < nv; s += 512) {
        int b = stb[s];
        ebuf[(size_t)b * BCAP + gbase[b] + (s - lofs[b])] = stp[s];
    }
}

// ---------- pass 2: inline base-prefix + per-bucket local sort -> csr ----------
// csr entries are SOURCE BYTE OFFSETS into the fp8 table (src*64); row for node n:
// [rowptr[n], rowptr[n+1]) with self-loop first. rowptr[N] set by last node.
__global__ __launch_bounds__(256) void k_scatter2(const u32* __restrict__ bucket_cnt,
                                                  const u32* __restrict__ ebuf,
                                                  int* __restrict__ rowptr,
                                                  float* __restrict__ dinv,
                                                  int* __restrict__ csr) {
    __shared__ u32 ssum[256];
    __shared__ u32 snev;
    __shared__ int cnt[256];
    __shared__ int pfx[256];
    __shared__ int lcur[256];
    int b = blockIdx.x, t = threadIdx.x;
    // inline exclusive prefix of bucket_cnt at b (sum of counts below b) + own count
    u32 a = 0;
    for (int i = t; i < NB; i += 256) {
        u32 cv = bucket_cnt[i];
        if (i < b) a += cv;
        if (i == b) snev = cv;
    }
    ssum[t] = a;
    __syncthreads();
    for (int off = 128; off >= 1; off >>= 1) {
        if (t < off) ssum[t] += ssum[t + off];
        __syncthreads();
    }
    int ebeg = (int)ssum[0];
    int ne = (int)snev;
    const u32* src = ebuf + (size_t)b * BCAP;
    int sbeg = ebeg + (b << 8);   // +1 self slot per node in prior (full) buckets
    cnt[t] = 0;
    lcur[t] = 0;
    __syncthreads();
    for (int i = t; i < ne; i += 256)
        atomicAdd(&cnt[(src[i] >> 20) & 255], 1);
    __syncthreads();
    int v = cnt[t];
    pfx[t] = v;
    __syncthreads();
    for (int off = 1; off < 256; off <<= 1) {
        int pv = (t >= off) ? pfx[t - off] : 0;
        __syncthreads();
        pfx[t] += pv;
        __syncthreads();
    }
    int node = (b << 8) + t;
    int rstart = sbeg + (pfx[t] - v) + t;
    if (node < N_NODES) {
        rowptr[node] = rstart;
        dinv[node] = rsqrtf((float)(v + 1));
        csr[rstart] = node << 6;            // self-loop, fp8-row byte offset
        if (node == N_NODES - 1) {
            rowptr[N_NODES] = rstart + v + 1;
            for (int i = 0; i < 64; ++i) csr[rstart + v + 1 + i] = 0;  // chunk-overrun pad
        }
    }
    __syncthreads();
    for (int i = t; i < ne; i += 256) {
        u32 p = src[i];
        int dl = (p >> 20) & 255;
        int pos = sbeg + (pfx[dl] - cnt[dl]) + dl + 1 + atomicAdd(&lcur[dl], 1);
        csr[pos] = (int)((p & 0x1FFFFu) << 6);   // src fp8-row byte offset
    }
}

// ---------- MFMA GEMM1: g1[N,64] = fp8( 16 * dinv ⊙ (x[N,256] @ W1[256,64]) ) ----------
__global__ __launch_bounds__(256) void k_gemm1(const void* __restrict__ xv,
                                               const u16* __restrict__ W1m,
                                               const float* __restrict__ dinv,
                                               u8* __restrict__ g1,
                                               const int* __restrict__ flags) {
    __shared__ u16 wlds[C_IN * C_H];   // 32 KB
    int t = threadIdx.x;
    int isbf = flags[0];
    {
        const uint4* src = (const uint4*)W1m;
        uint4* dst = (uint4*)wlds;
#pragma unroll
        for (int it = 0; it < 8; ++it) dst[t + it * 256] = src[t + it * 256];
    }
    __syncthreads();
    int w = t >> 6, lane = t & 63;
    int quad = lane >> 4, mrow = lane & 15;
    int m0 = blockIdx.x * 128 + w * 32;
    if (m0 >= N_NODES) return;

    bf16x8 a[2][8];
    if (isbf) {
        const u16* xb = (const u16*)xv;
#pragma unroll
        for (int mt = 0; mt < 2; ++mt)
#pragma unroll
            for (int k0 = 0; k0 < 8; ++k0)
                a[mt][k0] = *(const bf16x8*)(xb + (size_t)(m0 + mt * 16 + mrow) * C_IN + k0 * 32 + quad * 8);
    } else {
        const float* xf = (const float*)xv;
#pragma unroll
        for (int mt = 0; mt < 2; ++mt)
#pragma unroll
            for (int k0 = 0; k0 < 8; ++k0) {
                const float* p = xf + (size_t)(m0 + mt * 16 + mrow) * C_IN + k0 * 32 + quad * 8;
                float4 v0 = *(const float4*)p;
                float4 v1 = *(const float4*)(p + 4);
                bf16x8 r;
                r[0] = (short)f2bf(v0.x); r[1] = (short)f2bf(v0.y);
                r[2] = (short)f2bf(v0.z); r[3] = (short)f2bf(v0.w);
                r[4] = (short)f2bf(v1.x); r[5] = (short)f2bf(v1.y);
                r[6] = (short)f2bf(v1.z); r[7] = (short)f2bf(v1.w);
                a[mt][k0] = r;
            }
    }

    float dv0[4], dv1[4];
#pragma unroll
    for (int r = 0; r < 4; ++r) {
        dv0[r] = dinv[m0 + quad * 4 + r] * 16.f;
        dv1[r] = dinv[m0 + 16 + quad * 4 + r] * 16.f;
    }

#pragma unroll
    for (int nt = 0; nt < 4; ++nt) {
        bf16x8 b[8];
#pragma unroll
        for (int k0 = 0; k0 < 8; ++k0)
            b[k0] = *(const bf16x8*)&wlds[((k0 * 4 + nt) * 64 + lane) * 8];
        f32x4 acc0 = {0.f, 0.f, 0.f, 0.f};
        f32x4 acc1 = {0.f, 0.f, 0.f, 0.f};
#pragma unroll
        for (int k0 = 0; k0 < 8; ++k0) {
            acc0 = __builtin_amdgcn_mfma_f32_16x16x32_bf16(a[0][k0], b[k0], acc0, 0, 0, 0);
            acc1 = __builtin_amdgcn_mfma_f32_16x16x32_bf16(a[1][k0], b[k0], acc1, 0, 0, 0);
        }
        int ch = nt * 16 + mrow;   // D: col = lane&15
#pragma unroll
        for (int r = 0; r < 4; ++r) {   // D: row = quad*4 + r
            g1[(size_t)(m0 + quad * 4 + r) * C_H + ch] = f2fp8(acc0[r] * dv0[r]);
            g1[(size_t)(m0 + 16 + quad * 4 + r) * C_H + ch] = f2fp8(acc1[r] * dv1[r]);
        }
    }
}

// ---------- fp8 MFMA gather: out[16-node tile] = Sel(32 edges) x G(32 fp8 rows) ----------
// Table rows are 64 B fp8 (value*16); selector entries are 1/16 (0x18) so the
// MFMA yields the true sum. Per chunk: 2 csr loads + 2 gll16 (16 rows each,
// 4 lanes/row). Frags assembled via ds byte reads (deterministic layout:
// B[k=g16*8+j][ch=cht*16+c] at LDS byte (g16*8+j)*64 + cht*16 + c).
// MODE 0: out = fp8(16 * dinv * relu(dinv*sum + bias))   MODE 1: out = bf16(dinv*sum)
template <int MODE>
__global__ __launch_bounds__(256) void k_gatherM(const int* __restrict__ rowptr,
                                                 const int* __restrict__ csrb,
                                                 const float* __restrict__ dinv,
                                                 const u8* __restrict__ gt,
                                                 const float* __restrict__ bias,
                                                 void* __restrict__ out) {
    __shared__ __align__(16) u8 hsb[4][4096];   // per wave: 2 buffers x 2KB
    __shared__ u64 lut8[81];                    // selector runs, bytes of 0x18
    int t = threadIdx.x;
    if (t < 81) {
        int s = t / 9, e = t - s * 9;
        u32 lo = 0, hi = 0;
#pragma unroll
        for (int j = 0; j < 4; ++j) if (j >= s && j < e) lo |= 0x18u << (8 * j);
#pragma unroll
        for (int j = 4; j < 8; ++j) if (j >= s && j < e) hi |= 0x18u << (8 * (j - 4));
        lut8[t] = ((u64)hi << 32) | lo;
    }
    __syncthreads();
    int w = t >> 6, lane = t & 63;
    int tile = blockIdx.x * 4 + w;
    if (tile >= NT16) return;

    int g16 = lane >> 4, c = lane & 15;
    int n0 = tile << 4;
    int lo = rowptr[n0 + c];
    int hi = rowptr[n0 + c + 1];
    int beg = __shfl(lo, 0, 64);
    int end = __shfl(hi, 15, 64);
    int ridx = lane >> 2;           // row staged by this lane (16 rows per gll)
    int bq = (lane & 3) * 16;       // byte offset within 64B row
    const char* gb = (const char*)gt;
    u8* hw = hsb[w];
    f32x4 acc0 = {0.f, 0.f, 0.f, 0.f}, acc1 = acc0, acc2 = acc0, acc3 = acc0;
    int nch = (end - beg + 31) >> 5;
    int cb = beg;
    {   // prologue: stage chunk 0 into buffer 0
        u32 o0 = (u32)csrb[cb + ridx];
        u32 o1 = (u32)csrb[cb + 16 + ridx];
        gll16(gb + o0 + bq, hw);
        gll16(gb + o1 + bq, hw + 1024);
        asm volatile("" ::: "memory");   // pin: later loads can't hoist above glls
    }
    for (int ci = 0; ci < nch; ++ci) {
        int cbn = cb + 32;
        bool more = (ci + 1 < nch);
        u32 n0o = 0, n1o = 0;
        if (more) {                                   // issue next chunk's csr loads
            n0o = (u32)csrb[cbn + ridx];
            n1o = (u32)csrb[cbn + 16 + ridx];
        }
        if (more) asm volatile("s_waitcnt vmcnt(2)" ::: "memory");   // staging glls done
        else      asm volatile("s_waitcnt vmcnt(0)" ::: "memory");
        const u8* lp = hw + ((ci & 1) << 11) + g16 * 512 + c;
        int cbg = cb + g16 * 8;
        int s0 = min(max(lo - cbg, 0), 8);
        int e0 = min(max(hi - cbg, 0), 8);
        union P8 { u32 u[2]; long l; } pa, pb0, pb1, pb2, pb3;
        u64 av = lut8[s0 * 9 + e0];
        pa.u[0] = (u32)av; pa.u[1] = (u32)(av >> 32);
#define LDB(P, O)                                                                           \
        P.u[0] = (u32)lp[O] | ((u32)lp[O + 64] << 8) | ((u32)lp[O + 128] << 16) |           \
                 ((u32)lp[O + 192] << 24);                                                  \
        P.u[1] = (u32)lp[O + 256] | ((u32)lp[O + 320] << 8) | ((u32)lp[O + 384] << 16) |    \
                 ((u32)lp[O + 448] << 24);
        LDB(pb0, 0) LDB(pb1, 16) LDB(pb2, 32) LDB(pb3, 48)
#undef LDB
        acc0 = __builtin_amdgcn_mfma_f32_16x16x32_fp8_fp8(pa.l, pb0.l, acc0, 0, 0, 0);
        acc1 = __builtin_amdgcn_mfma_f32_16x16x32_fp8_fp8(pa.l, pb1.l, acc1, 0, 0, 0);
        acc2 = __builtin_amdgcn_mfma_f32_16x16x32_fp8_fp8(pa.l, pb2.l, acc2, 0, 0, 0);
        acc3 = __builtin_amdgcn_mfma_f32_16x16x32_fp8_fp8(pa.l, pb3.l, acc3, 0, 0, 0);
        if (more) {                                   // stage next chunk, other buffer
            int bo = ((ci + 1) & 1) << 11;
            gll16(gb + n0o + bq, hw + bo);
            gll16(gb + n1o + bq, hw + bo + 1024);
            asm volatile("" ::: "memory");   // pin: next iter's csr loads stay below
        }
        cb = cbn;
    }
    // epilogue: D row = node (lane>>4)*4+r, D col = channel cht*16 + (lane&15)
    float dv[4];
    int nb = n0 + g16 * 4;
#pragma unroll
    for (int r = 0; r < 4; ++r) dv[r] = dinv[nb + r];
    if (MODE == 0) {
        u8* ob = (u8*)out + (size_t)nb * C_H + c;
#define EPI(ACC, CHT)                                                                       \
        {                                                                                   \
            float bs = bias[CHT * 16 + c];                                                  \
            _Pragma("unroll")                                                               \
            for (int r = 0; r < 4; ++r)                                                     \
                ob[r * C_H + CHT * 16] =                                                    \
                    f2fp8(16.f * dv[r] * fmaxf(dv[r] * ACC[r] + bs, 0.f));                  \
        }
        EPI(acc0, 0) EPI(acc1, 1) EPI(acc2, 2) EPI(acc3, 3)
#undef EPI
    } else {
        u16* ob = (u16*)out + (size_t)nb * C_H + c;
#define EPI(ACC, CHT)                                                                       \
        {                                                                                   \
            _Pragma("unroll")                                                               \
            for (int r = 0; r < 4; ++r)                                                     \
                ob[r * C_H + CHT * 16] = f2bf(dv[r] * ACC[r]);                              \
        }
        EPI(acc0, 0) EPI(acc1, 1) EPI(acc2, 2) EPI(acc3, 3)
#undef EPI
    }
}

// ---------- fused MFMA GEMM2 + bias + relu + mean-pool partials ----------
__global__ __launch_bounds__(256) void k_fused2(const u16* __restrict__ aggb,
                                                const u16* __restrict__ W2m,
                                                const float* __restrict__ b2c,
                                                float* __restrict__ partial) {
    __shared__ float psum[4 * 8 * 64];   // [wave][nt][lane], 8 KB
    int t = threadIdx.x;
    int w = t >> 6, lane = t & 63;
    int quad = lane >> 4, m = lane & 15;

    bf16x8 b[2][8];
#pragma unroll
    for (int k0 = 0; k0 < 2; ++k0)
#pragma unroll
        for (int nt = 0; nt < 8; ++nt)
            b[k0][nt] = *(const bf16x8*)&W2m[((k0 * 8 + nt) * 64 + lane) * 8];

    float pacc[8] = {0.f, 0.f, 0.f, 0.f, 0.f, 0.f, 0.f, 0.f};
    float bias[8];
#pragma unroll
    for (int nt = 0; nt < 8; ++nt) bias[nt] = b2c[nt * 16 + m];

    for (int tile = blockIdx.x * 4 + w; tile < NTILES; tile += G2F * 4) {
        const u16* arow = aggb + (size_t)(tile * 16 + m) * C_H + quad * 8;
        bf16x8 a0 = *(const bf16x8*)(arow);
        bf16x8 a1 = *(const bf16x8*)(arow + 32);
#pragma unroll
        for (int nt = 0; nt < 8; ++nt) {
            f32x4 acc = {0.f, 0.f, 0.f, 0.f};
            acc = __builtin_amdgcn_mfma_f32_16x16x32_bf16(a0, b[0][nt], acc, 0, 0, 0);
            acc = __builtin_amdgcn_mfma_f32_16x16x32_bf16(a1, b[1][nt], acc, 0, 0, 0);
#pragma unroll
            for (int r = 0; r < 4; ++r)
                pacc[nt] += fmaxf(acc[r] + bias[nt], 0.f);
        }
    }
#pragma unroll
    for (int nt = 0; nt < 8; ++nt) psum[(w * 8 + nt) * 64 + lane] = pacc[nt];
    __syncthreads();
    if (t < 128) {
        int nt = t >> 4, m2 = t & 15;
        float s = 0.f;
#pragma unroll
        for (int ww = 0; ww < 4; ++ww)
#pragma unroll
            for (int q = 0; q < 4; ++q)
                s += psum[(ww * 8 + nt) * 64 + q * 16 + m2];
        partial[blockIdx.x * C_OUT + t] = s;   // ch = nt*16 + m2 = t
    }
}

// ---------- final: mean + FC -> 2 outputs (dtype per flag) ----------
__global__ __launch_bounds__(512) void k_final(const float* __restrict__ partial,
                                               const float* __restrict__ fcWc,
                                               const float* __restrict__ fcbc,
                                               void* __restrict__ out,
                                               const int* __restrict__ flags) {
    __shared__ float sm[512];
    __shared__ float red[256];
    int t = threadIdx.x;
    int f = t & 127, c = t >> 7;
    float s = 0.f;
    for (int b = c; b < G2F; b += 4) s += partial[b * 128 + f];
    sm[t] = s;
    __syncthreads();
    if (t < 128) {
        float gm = (sm[t] + sm[t + 128] + sm[t + 256] + sm[t + 384]) * (1.0f / (float)N_NODES);
        red[t] = gm * fcWc[t];
        red[128 + t] = gm * fcWc[128 + t];
    }
    __syncthreads();
    for (int off = 64; off >= 1; off >>= 1) {
        if (t < off) {
            red[t] += red[t + off];
            red[128 + t] += red[128 + t + off];
        }
        __syncthreads();
    }
    if (t == 0) {
        float o0 = red[0] + fcbc[0];
        float o1 = red[128] + fcbc[1];
        if (flags[0]) {
            u16* ob = (u16*)out;
            ob[0] = f2bf(o0);
            ob[1] = f2bf(o1);
        } else {
            float* of = (float*)out;
            of[0] = o0;
            of[1] = o1;
        }
    }
}

// ---------- workspace layout (bytes) ----------
// csr int[E + NB*256 + pad] = 13,200,384 B. g1/a1s now fp8 (6.4MB each; regions
// keep their old 12.8MB spacing). ebuf dedicated u32[NB*BCAP] (25.6MB).
#define OFF_FLAGS   0u
#define OFF_DINV    512u         // float[N]
#define OFF_ROWPTR  400896u      // int[N+1]
#define OFF_BCNT    801280u      // u32[NB]
#define OFF_CSR     1201664u     // int[3300096]
#define OFF_H1      14402560u    // fp8[N*64]  (g1 = 16*dinv*h1)
#define OFF_A1      27202560u    // fp8[N*64]  (a1s = 16*dinv*relu(conv1))
#define OFF_AGG     40002560u    // bf16[N*64]
#define OFF_PART    52802560u    // float[G2F*128]
#define OFF_W1C     53122560u    // u16[256*64] (MFMA frag order)
#define OFF_W2C     53155328u    // u16[64*128] (MFMA frag order)
#define OFF_B1C     53171712u    // float[64]
#define OFF_B2C     53171968u    // float[128]
#define OFF_FCWC    53172480u    // float[256]
#define OFF_FCBC    53173504u    // float[2]
#define OFF_EBUF    53174272u    // u32[NB*BCAP] = 25,624,576 B (ends ~78.8MB)

extern "C" void kernel_launch(void* const* d_in, const int* in_sizes, int n_in,
                              void* d_out, int out_size, void* d_ws, size_t ws_size,
                              hipStream_t stream) {
    (void)in_sizes; (void)n_in; (void)out_size; (void)ws_size;
    const void* x   = d_in[0];
    const int*  ei  = (const int*)d_in[1];
    const void* W1  = d_in[2];
    const void* b1  = d_in[3];
    const void* W2  = d_in[4];
    const void* b2  = d_in[5];
    const void* fcW = d_in[6];
    const void* fcb = d_in[7];

    char* ws = (char*)d_ws;
    int*   flags  = (int*)(ws + OFF_FLAGS);
    float* dinv   = (float*)(ws + OFF_DINV);
    int*   rowptr = (int*)(ws + OFF_ROWPTR);
    u32*   bcnt   = (u32*)(ws + OFF_BCNT);
    int*   csr    = (int*)(ws + OFF_CSR);
    u8*    g1     = (u8*)(ws + OFF_H1);
    u8*    a1s    = (u8*)(ws + OFF_A1);
    u16*   aggb   = (u16*)(ws + OFF_AGG);
    u32*   ebuf   = (u32*)(ws + OFF_EBUF);
    float* partial= (float*)(ws + OFF_PART);
    u16*   W1m    = (u16*)(ws + OFF_W1C);
    u16*   W2m    = (u16*)(ws + OFF_W2C);
    float* b1c    = (float*)(ws + OFF_B1C);
    float* b2c    = (float*)(ws + OFF_B2C);
    float* fcWc   = (float*)(ws + OFF_FCWC);
    float* fcbc   = (float*)(ws + OFF_FCBC);

    k_prep<<<96, 256, 0, stream>>>(x, ei, W1, W2, b1, b2, fcW, fcb,
                                   flags, W1m, W2m, bcnt, b1c, b2c, fcWc, fcbc);
    k_scatter1<<<NB, 512, 0, stream>>>(ei, flags, bcnt, ebuf);
    k_scatter2<<<NB, 256, 0, stream>>>(bcnt, ebuf, rowptr, dinv, csr);
    k_gemm1<<<(N_NODES + 127) / 128, 256, 0, stream>>>(x, W1m, dinv, g1, flags);
    k_gatherM<0><<<G_GM, 256, 0, stream>>>(rowptr, csr, dinv, g1, b1c, (void*)a1s);
    k_gatherM<1><<<G_GM, 256, 0, stream>>>(rowptr, csr, dinv, a1s, b2c, (void*)aggb);
    k_fused2<<<G2F, 256, 0, stream>>>(aggb, W2m, b2c, partial);
    k_final<<<1, 512, 0, stream>>>(partial, fcWc, fcbc, (void*)d_out, flags);
}

// Round 7
// 357.683 us; speedup vs baseline: 1.1431x; 1.0101x over previous
//
#include <hip/hip_runtime.h>

#define N_NODES 100000
#define N_EDGES 3200000
#define C_IN 256
#define C_H 64
#define C_OUT 128
#define NB 391       // ceil(N_NODES/256) buckets of 256 nodes
#define BCAP 16384   // fixed per-bucket capacity in ebuf (mean 8184, 2x headroom)
#define G2F 625      // blocks for fused gemm2+pool
#define NTILES 6250  // N_NODES/16
#define NT16 6250    // gather tiles of 16 nodes
#define G_GM 1563    // ceil(NT16/4)
#define CH1 8192     // edges per block in scatter1

typedef unsigned int u32;
typedef unsigned short u16;
typedef unsigned char u8;
typedef unsigned long long u64;
typedef __attribute__((ext_vector_type(8))) short bf16x8;
typedef __attribute__((ext_vector_type(4))) float f32x4;

typedef __attribute__((address_space(3))) unsigned int l_u32;
typedef __attribute__((address_space(1))) const unsigned int g_u32;

// ---------- bf16 / fp8 helpers ----------
__device__ __forceinline__ float bf2f(u16 u) {
    union { u32 i; float f; } v; v.i = ((u32)u) << 16; return v.f;
}
__device__ __forceinline__ u16 f2bf(float f) {
    union { float f; u32 i; } v; v.f = f;
    u32 x = v.i;
    return (u16)((x + 0x7fffu + ((x >> 16) & 1u)) >> 16);  // RNE
}
// f32 -> OCP e4m3fn, RNE, saturate to 448
__device__ __forceinline__ u8 f2fp8(float f) {
    union { float f; u32 i; } v; v.f = f;
    u32 s = (v.i >> 24) & 0x80u;
    float a = __builtin_fabsf(f);
    a = fminf(a, 448.f);
    if (a < 0.015625f) {                              // subnormal region, step 2^-9
        int m = (int)__builtin_rintf(a * 512.f);      // 0..8 (8 carries to 2^-6)
        return (u8)(s | (u32)m);
    }
    union { float ff; u32 i; } w; w.ff = a;
    u32 x = w.i;
    u32 r = x + 0x7FFFFu + ((x >> 20) & 1u);          // RNE into 3-bit mantissa
    u32 E = (r >> 23) - 120u;                         // 1..15
    u32 m = (r >> 20) & 7u;
    return (u8)(s | (E << 3) | m);
}

__device__ __forceinline__ void gll16(const void* gp, const void* lp) {
    __builtin_amdgcn_global_load_lds((g_u32*)gp, (l_u32*)lp, 16, 0, 0);
}

// 4x4 byte transpose: r_c = bytes {a0[c],a1[c],a2[c],a3[c]} (little-endian byte0 first)
#define BT4(a0, a1, a2, a3, r0, r1, r2, r3)                          \
    {                                                                \
        u32 t0 = (a0 & 0x00ff00ffu) | ((a1 & 0x00ff00ffu) << 8);     \
        u32 t1 = ((a0 >> 8) & 0x00ff00ffu) | (a1 & 0xff00ff00u);     \
        u32 t2 = (a2 & 0x00ff00ffu) | ((a3 & 0x00ff00ffu) << 8);     \
        u32 t3 = ((a2 >> 8) & 0x00ff00ffu) | (a3 & 0xff00ff00u);     \
        r0 = (t0 & 0xffffu) | (t2 << 16);                            \
        r2 = (t0 >> 16) | (t2 & 0xffff0000u);                        \
        r1 = (t1 & 0xffffu) | (t3 << 16);                            \
        r3 = (t1 >> 16) | (t3 & 0xffff0000u);                        \
    }

// ---------- prep: detect flags + small-tensor conversions + W swizzles + bcnt zero ----------
__global__ __launch_bounds__(256) void k_prep(const void* __restrict__ x, const void* __restrict__ ei,
                                              const void* __restrict__ W1, const void* __restrict__ W2,
                                              const void* __restrict__ b1, const void* __restrict__ b2,
                                              const void* __restrict__ fcW, const void* __restrict__ fcb,
                                              int* __restrict__ flags,
                                              u16* __restrict__ W1m, u16* __restrict__ W2m,
                                              u32* __restrict__ bucket_cnt,
                                              float* __restrict__ b1c, float* __restrict__ b2c,
                                              float* __restrict__ fcWc, float* __restrict__ fcbc) {
    __shared__ int sfb;
    int b = blockIdx.x, t = threadIdx.x;
    if (t < 64) {
        u32 wv = ((const u32*)x)[t];
        u32 low = wv & 0xffffu;
        int e = (int)((low >> 7) & 0xff);
        bool inw = (e > 96 && e < 160) || (low == 0);
        u64 m = __ballot(inw);
        if (t == 0) sfb = (__popcll(m) >= 60) ? 1 : 0;
    } else if (b == 0 && t < 128) {
        int i = t - 64;
        u32 wv = ((const u32*)ei)[2 * i + 1];
        u64 m = __ballot(wv == 0);
        if (i == 0) flags[1] = (m == ~0ull) ? 1 : 0;
    }
    __syncthreads();
    int isbf = sfb;
    if (b == 0 && t == 0) flags[0] = isbf;
    int i = b * 256 + t;
    if (i < NB) bucket_cnt[i] = 0;
    if (i < C_IN * C_H) {
        const u16* w1b = (const u16*)W1; const float* w1f = (const float*)W1;
        int j = i & 7, lane = (i >> 3) & 63, nt = (i >> 9) & 3, k0 = i >> 11;
        int k = k0 * 32 + ((lane >> 4) & 3) * 8 + j;
        int n = nt * 16 + (lane & 15);
        W1m[i] = isbf ? w1b[k * C_H + n] : f2bf(w1f[k * C_H + n]);
    } else {
        int i2 = i - C_IN * C_H;
        const u16* w2b = (const u16*)W2; const float* w2f = (const float*)W2;
        int j = i2 & 7, lane = (i2 >> 3) & 63, nt = (i2 >> 9) & 7, k0 = (i2 >> 12) & 1;
        int k = k0 * 32 + ((lane >> 4) & 3) * 8 + j;
        int n = nt * 16 + (lane & 15);
        W2m[i2] = isbf ? w2b[k * C_OUT + n] : f2bf(w2f[k * C_OUT + n]);
    }
    if (b == 0) {
        if (isbf) {
            const u16* p1 = (const u16*)b1;  const u16* p2 = (const u16*)b2;
            const u16* pw = (const u16*)fcW; const u16* pb = (const u16*)fcb;
            for (int q = t; q < C_H; q += 256) b1c[q] = bf2f(p1[q]);
            for (int q = t; q < C_OUT; q += 256) b2c[q] = bf2f(p2[q]);
            for (int q = t; q < 2 * C_OUT; q += 256) fcWc[q] = bf2f(pw[q]);
            for (int q = t; q < 2; q += 256) fcbc[q] = bf2f(pb[q]);
        } else {
            const float* p1 = (const float*)b1;  const float* p2 = (const float*)b2;
            const float* pw = (const float*)fcW; const float* pb = (const float*)fcb;
            for (int q = t; q < C_H; q += 256) b1c[q] = p1[q];
            for (int q = t; q < C_OUT; q += 256) b2c[q] = p2[q];
            for (int q = t; q < 2 * C_OUT; q += 256) fcWc[q] = pw[q];
            for (int q = t; q < 2; q += 256) fcbc[q] = pb[q];
        }
    }
}

// ---------- pass 1: bucket-sorted staged scatter into fixed-capacity buckets ----------
// bucket_cnt doubles as the allocation cursor (starts 0, ends = count).
__global__ __launch_bounds__(512) void k_scatter1(const int* __restrict__ ei,
                                                  const int* __restrict__ flags,
                                                  u32* __restrict__ bucket_cnt,
                                                  u32* __restrict__ ebuf) {
    __shared__ u32 cnt[NB];
    __shared__ u32 lcur[NB];
    __shared__ u32 gbase[NB];
    __shared__ u32 lofs[512];
    __shared__ u32 stp[CH1];
    __shared__ u16 stb[CH1];
    int t = threadIdx.x;
    int is64 = flags[1];
    int e0 = blockIdx.x * CH1;
    int nv = min(CH1, N_EDGES - e0);
    for (int i = t; i < NB; i += 512) { cnt[i] = 0; lcur[i] = 0; }
    __syncthreads();
    for (int i = t; i < nv; i += 512) {
        int e = e0 + i;
        int d = is64 ? ei[2 * (N_EDGES + e)] : ei[N_EDGES + e];
        atomicAdd(&cnt[d >> 8], 1u);
    }
    __syncthreads();
    u32 v = (t < NB) ? cnt[t] : 0;
    lofs[t] = v;
    __syncthreads();
    for (int off = 1; off < 512; off <<= 1) {
        u32 a = (t >= off) ? lofs[t - off] : 0;
        __syncthreads();
        lofs[t] += a;
        __syncthreads();
    }
    u32 excl = lofs[t] - v;
    __syncthreads();
    lofs[t] = excl;
    __syncthreads();
    for (int i = t; i < nv; i += 512) {
        int e = e0 + i;
        int d, s;
        if (is64) { d = ei[2 * (N_EDGES + e)]; s = ei[2 * e]; }
        else      { d = ei[N_EDGES + e];       s = ei[e]; }
        int b = d >> 8;
        u32 slot = lofs[b] + atomicAdd(&lcur[b], 1u);
        stp[slot] = ((u32)(d & 255) << 20) | (u32)s;
        stb[slot] = (u16)b;
    }
    __syncthreads();
    for (int b = t; b < NB; b += 512) {
        u32 c = cnt[b];
        gbase[b] = c ? atomicAdd(&bucket_cnt[b], c) : 0;
    }
    __syncthreads();
    for (int s = t; s < nv; s += 512) {
        int b = stb[s];
        ebuf[(size_t)b * BCAP + gbase[b] + (s - lofs[b])] = stp[s];
    }
}

// ---------- pass 2: inline base-prefix + per-bucket local sort -> csr ----------
// csr entries are SOURCE BYTE OFFSETS into the fp8 table (src*64); row for node n:
// [rowptr[n], rowptr[n+1]) with self-loop first. rowptr[N] set by last node.
__global__ __launch_bounds__(256) void k_scatter2(const u32* __restrict__ bucket_cnt,
                                                  const u32* __restrict__ ebuf,
                                                  int* __restrict__ rowptr,
                                                  float* __restrict__ dinv,
                                                  int* __restrict__ csr) {
    __shared__ u32 ssum[256];
    __shared__ u32 snev;
    __shared__ int cnt[256];
    __shared__ int pfx[256];
    __shared__ int lcur[256];
    int b = blockIdx.x, t = threadIdx.x;
    // inline exclusive prefix of bucket_cnt at b (sum of counts below b) + own count
    u32 a = 0;
    for (int i = t; i < NB; i += 256) {
        u32 cv = bucket_cnt[i];
        if (i < b) a += cv;
        if (i == b) snev = cv;
    }
    ssum[t] = a;
    __syncthreads();
    for (int off = 128; off >= 1; off >>= 1) {
        if (t < off) ssum[t] += ssum[t + off];
        __syncthreads();
    }
    int ebeg = (int)ssum[0];
    int ne = (int)snev;
    const u32* src = ebuf + (size_t)b * BCAP;
    int sbeg = ebeg + (b << 8);   // +1 self slot per node in prior (full) buckets
    cnt[t] = 0;
    lcur[t] = 0;
    __syncthreads();
    for (int i = t; i < ne; i += 256)
        atomicAdd(&cnt[(src[i] >> 20) & 255], 1);
    __syncthreads();
    int v = cnt[t];
    pfx[t] = v;
    __syncthreads();
    for (int off = 1; off < 256; off <<= 1) {
        int pv = (t >= off) ? pfx[t - off] : 0;
        __syncthreads();
        pfx[t] += pv;
        __syncthreads();
    }
    int node = (b << 8) + t;
    int rstart = sbeg + (pfx[t] - v) + t;
    if (node < N_NODES) {
        rowptr[node] = rstart;
        dinv[node] = rsqrtf((float)(v + 1));
        csr[rstart] = node << 6;            // self-loop, fp8-row byte offset
        if (node == N_NODES - 1) {
            rowptr[N_NODES] = rstart + v + 1;
            for (int i = 0; i < 64; ++i) csr[rstart + v + 1 + i] = 0;  // chunk-overrun pad
        }
    }
    __syncthreads();
    for (int i = t; i < ne; i += 256) {
        u32 p = src[i];
        int dl = (p >> 20) & 255;
        int pos = sbeg + (pfx[dl] - cnt[dl]) + dl + 1 + atomicAdd(&lcur[dl], 1);
        csr[pos] = (int)((p & 0x1FFFFu) << 6);   // src fp8-row byte offset
    }
}

// ---------- MFMA GEMM1: g1[N,64] = fp8( 16 * dinv ⊙ (x @ W1) ), PERMUTED row bytes ----------
// Row byte order: pos(ch) = (ch&15)*4 + (ch>>4), so channels {c,c+16,c+32,c+48}
// form one contiguous u32 at byte c*4 (consumed by the gather as a single b32).
__global__ __launch_bounds__(256) void k_gemm1(const void* __restrict__ xv,
                                               const u16* __restrict__ W1m,
                                               const float* __restrict__ dinv,
                                               u8* __restrict__ g1,
                                               const int* __restrict__ flags) {
    __shared__ u16 wlds[C_IN * C_H];   // 32 KB
    int t = threadIdx.x;
    int isbf = flags[0];
    {
        const uint4* src = (const uint4*)W1m;
        uint4* dst = (uint4*)wlds;
#pragma unroll
        for (int it = 0; it < 8; ++it) dst[t + it * 256] = src[t + it * 256];
    }
    __syncthreads();
    int w = t >> 6, lane = t & 63;
    int quad = lane >> 4, mrow = lane & 15;
    int m0 = blockIdx.x * 128 + w * 32;
    if (m0 >= N_NODES) return;

    bf16x8 a[2][8];
    if (isbf) {
        const u16* xb = (const u16*)xv;
#pragma unroll
        for (int mt = 0; mt < 2; ++mt)
#pragma unroll
            for (int k0 = 0; k0 < 8; ++k0)
                a[mt][k0] = *(const bf16x8*)(xb + (size_t)(m0 + mt * 16 + mrow) * C_IN + k0 * 32 + quad * 8);
    } else {
        const float* xf = (const float*)xv;
#pragma unroll
        for (int mt = 0; mt < 2; ++mt)
#pragma unroll
            for (int k0 = 0; k0 < 8; ++k0) {
                const float* p = xf + (size_t)(m0 + mt * 16 + mrow) * C_IN + k0 * 32 + quad * 8;
                float4 v0 = *(const float4*)p;
                float4 v1 = *(const float4*)(p + 4);
                bf16x8 r;
                r[0] = (short)f2bf(v0.x); r[1] = (short)f2bf(v0.y);
                r[2] = (short)f2bf(v0.z); r[3] = (short)f2bf(v0.w);
                r[4] = (short)f2bf(v1.x); r[5] = (short)f2bf(v1.y);
                r[6] = (short)f2bf(v1.z); r[7] = (short)f2bf(v1.w);
                a[mt][k0] = r;
            }
    }

    float dv0[4], dv1[4];
#pragma unroll
    for (int r = 0; r < 4; ++r) {
        dv0[r] = dinv[m0 + quad * 4 + r] * 16.f;
        dv1[r] = dinv[m0 + 16 + quad * 4 + r] * 16.f;
    }

#pragma unroll
    for (int nt = 0; nt < 4; ++nt) {
        bf16x8 b[8];
#pragma unroll
        for (int k0 = 0; k0 < 8; ++k0)
            b[k0] = *(const bf16x8*)&wlds[((k0 * 4 + nt) * 64 + lane) * 8];
        f32x4 acc0 = {0.f, 0.f, 0.f, 0.f};
        f32x4 acc1 = {0.f, 0.f, 0.f, 0.f};
#pragma unroll
        for (int k0 = 0; k0 < 8; ++k0) {
            acc0 = __builtin_amdgcn_mfma_f32_16x16x32_bf16(a[0][k0], b[k0], acc0, 0, 0, 0);
            acc1 = __builtin_amdgcn_mfma_f32_16x16x32_bf16(a[1][k0], b[k0], acc1, 0, 0, 0);
        }
        int pos = mrow * 4 + nt;   // ch = nt*16 + mrow -> permuted byte pos
#pragma unroll
        for (int r = 0; r < 4; ++r) {   // D: row = quad*4 + r
            g1[(size_t)(m0 + quad * 4 + r) * C_H + pos] = f2fp8(acc0[r] * dv0[r]);
            g1[(size_t)(m0 + 16 + quad * 4 + r) * C_H + pos] = f2fp8(acc1[r] * dv1[r]);
        }
    }
}

// ---------- fp8 MFMA gather, u32-per-row fragment loads ----------
// Table rows: 64B fp8 (value*16), byte pos(ch) = (ch&15)*4 + (ch>>4).
// Chunk = 32 rows staged via 2 gll16 with block permutation b = j*16 + g16*4 + s
// (j=row&7 [inst0: 0..3, inst1: 4..7], g16=row>>3, s=16B-subblock): per-lane
// global src = csr_row + s*16, linear LDS dest. Fragment loads for lane (cg,c):
// u32 at LDS index j*64 + cg*16 + c  (one u32 = the 4 per-fragment bytes of row
// cg*8+j) — bank = 16*(cg&1)+c: exactly 2-way, free. 4x4 byte transpose (BT4)
// rebuilds the 4 fragments. Selector A = 1/16-run LUT (table holds value*16).
// MODE 0: out = fp8 permuted (16*dinv*relu(dinv*sum+bias))  MODE 1: out = bf16 std
template <int MODE>
__global__ __launch_bounds__(256) void k_gatherM(const int* __restrict__ rowptr,
                                                 const int* __restrict__ csrb,
                                                 const float* __restrict__ dinv,
                                                 const u8* __restrict__ gt,
                                                 const float* __restrict__ bias,
                                                 void* __restrict__ out) {
    __shared__ __align__(16) u8 hsb[4][4096];   // per wave: 2 buffers x 2KB
    __shared__ u64 lut8[81];                    // selector runs, bytes of 0x18
    int t = threadIdx.x;
    if (t < 81) {
        int s = t / 9, e = t - s * 9;
        u32 lo = 0, hi = 0;
#pragma unroll
        for (int j = 0; j < 4; ++j) if (j >= s && j < e) lo |= 0x18u << (8 * j);
#pragma unroll
        for (int j = 4; j < 8; ++j) if (j >= s && j < e) hi |= 0x18u << (8 * (j - 4));
        lut8[t] = ((u64)hi << 32) | lo;
    }
    __syncthreads();
    int w = t >> 6, lane = t & 63;
    int tile = blockIdx.x * 4 + w;
    if (tile >= NT16) return;

    int cg = lane >> 4, c = lane & 15;
    int n0 = tile << 4;
    int lo = rowptr[n0 + c];
    int hi = rowptr[n0 + c + 1];
    int beg = __shfl(lo, 0, 64);
    int end = __shfl(hi, 15, 64);
    // staging roles: block = inst*64 + lane; decode j=blk>>4, g=( blk>>2)&3, s=blk&3
    int rowA = ((lane >> 2) & 3) * 8 + (lane >> 4);        // inst0 row (j=0..3)
    int rowB = rowA + 4;                                   // inst1 row (j=4..7)
    int s16 = (lane & 3) * 16;                             // subblock byte offset
    const char* gb = (const char*)gt;
    u8* hw = hsb[w];
    int bi = cg * 16 + c;                                  // fragment u32 index base
    f32x4 acc0 = {0.f, 0.f, 0.f, 0.f}, acc1 = acc0, acc2 = acc0, acc3 = acc0;
    int nch = (end - beg + 31) >> 5;
    int cb = beg;
    {   // prologue: stage chunk 0 into buffer 0
        u32 oA = (u32)csrb[cb + rowA];
        u32 oB = (u32)csrb[cb + rowB];
        gll16(gb + oA + s16, hw);
        gll16(gb + oB + s16, hw + 1024);
        asm volatile("" ::: "memory");   // pin: later loads can't hoist above glls
    }
    for (int ci = 0; ci < nch; ++ci) {
        int cbn = cb + 32;
        bool more = (ci + 1 < nch);
        u32 nA = 0, nB = 0;
        if (more) {                                   // issue next chunk's csr loads
            nA = (u32)csrb[cbn + rowA];
            nB = (u32)csrb[cbn + rowB];
        }
        if (more) asm volatile("s_waitcnt vmcnt(2)" ::: "memory");   // staging glls done
        else      asm volatile("s_waitcnt vmcnt(0)" ::: "memory");
        const u32* hb = (const u32*)(hw + ((ci & 1) << 11));
        u32 w0 = hb[bi], w1 = hb[bi + 64], w2 = hb[bi + 128], w3 = hb[bi + 192];
        u32 w4 = hb[bi + 256], w5 = hb[bi + 320], w6 = hb[bi + 384], w7 = hb[bi + 448];
        u32 l0, l1, l2, l3, h0, h1, h2, h3;
        BT4(w0, w1, w2, w3, l0, l1, l2, l3)
        BT4(w4, w5, w6, w7, h0, h1, h2, h3)
        int cbg = cb + cg * 8;
        int s0 = min(max(lo - cbg, 0), 8);
        int e0 = min(max(hi - cbg, 0), 8);
        union P8 { u32 u[2]; long l; } pa, pb0, pb1, pb2, pb3;
        u64 av = lut8[s0 * 9 + e0];
        pa.u[0] = (u32)av; pa.u[1] = (u32)(av >> 32);
        pb0.u[0] = l0; pb0.u[1] = h0;
        pb1.u[0] = l1; pb1.u[1] = h1;
        pb2.u[0] = l2; pb2.u[1] = h2;
        pb3.u[0] = l3; pb3.u[1] = h3;
        acc0 = __builtin_amdgcn_mfma_f32_16x16x32_fp8_fp8(pa.l, pb0.l, acc0, 0, 0, 0);
        acc1 = __builtin_amdgcn_mfma_f32_16x16x32_fp8_fp8(pa.l, pb1.l, acc1, 0, 0, 0);
        acc2 = __builtin_amdgcn_mfma_f32_16x16x32_fp8_fp8(pa.l, pb2.l, acc2, 0, 0, 0);
        acc3 = __builtin_amdgcn_mfma_f32_16x16x32_fp8_fp8(pa.l, pb3.l, acc3, 0, 0, 0);
        if (more) {                                   // stage next chunk, other buffer
            int bo = ((ci + 1) & 1) << 11;
            gll16(gb + nA + s16, hw + bo);
            gll16(gb + nB + s16, hw + bo + 1024);
            asm volatile("" ::: "memory");   // pin: next iter's csr loads stay below
        }
        cb = cbn;
    }
    // epilogue: D row = node cg*4+q, D col = channel cht*16 + c
    float dv[4];
    int nb = n0 + cg * 4;
#pragma unroll
    for (int q = 0; q < 4; ++q) dv[q] = dinv[nb + q];
    if (MODE == 0) {   // fp8 table out, permuted byte order pos = c*4 + cht
        u8* ob = (u8*)out + (size_t)nb * C_H + c * 4;
#define EPI(ACC, CHT)                                                                       \
        {                                                                                   \
            float bs = bias[CHT * 16 + c];                                                  \
            _Pragma("unroll")                                                               \
            for (int q = 0; q < 4; ++q)                                                     \
                ob[q * C_H + CHT] =                                                         \
                    f2fp8(16.f * dv[q] * fmaxf(dv[q] * ACC[q] + bs, 0.f));                  \
        }
        EPI(acc0, 0) EPI(acc1, 1) EPI(acc2, 2) EPI(acc3, 3)
#undef EPI
    } else {           // bf16 out, standard channel order
        u16* ob = (u16*)out + (size_t)nb * C_H + c;
#define EPI(ACC, CHT)                                                                       \
        {                                                                                   \
            _Pragma("unroll")                                                               \
            for (int q = 0; q < 4; ++q)                                                     \
                ob[q * C_H + CHT * 16] = f2bf(dv[q] * ACC[q]);                              \
        }
        EPI(acc0, 0) EPI(acc1, 1) EPI(acc2, 2) EPI(acc3, 3)
#undef EPI
    }
}

// ---------- fused MFMA GEMM2 + bias + relu + mean-pool partials ----------
__global__ __launch_bounds__(256) void k_fused2(const u16* __restrict__ aggb,
                                                const u16* __restrict__ W2m,
                                                const float* __restrict__ b2c,
                                                float* __restrict__ partial) {
    __shared__ float psum[4 * 8 * 64];   // [wave][nt][lane], 8 KB
    int t = threadIdx.x;
    int w = t >> 6, lane = t & 63;
    int quad = lane >> 4, m = lane & 15;

    bf16x8 b[2][8];
#pragma unroll
    for (int k0 = 0; k0 < 2; ++k0)
#pragma unroll
        for (int nt = 0; nt < 8; ++nt)
            b[k0][nt] = *(const bf16x8*)&W2m[((k0 * 8 + nt) * 64 + lane) * 8];

    float pacc[8] = {0.f, 0.f, 0.f, 0.f, 0.f, 0.f, 0.f, 0.f};
    float bias[8];
#pragma unroll
    for (int nt = 0; nt < 8; ++nt) bias[nt] = b2c[nt * 16 + m];

    for (int tile = blockIdx.x * 4 + w; tile < NTILES; tile += G2F * 4) {
        const u16* arow = aggb + (size_t)(tile * 16 + m) * C_H + quad * 8;
        bf16x8 a0 = *(const bf16x8*)(arow);
        bf16x8 a1 = *(const bf16x8*)(arow + 32);
#pragma unroll
        for (int nt = 0; nt < 8; ++nt) {
            f32x4 acc = {0.f, 0.f, 0.f, 0.f};
            acc = __builtin_amdgcn_mfma_f32_16x16x32_bf16(a0, b[0][nt], acc, 0, 0, 0);
            acc = __builtin_amdgcn_mfma_f32_16x16x32_bf16(a1, b[1][nt], acc, 0, 0, 0);
#pragma unroll
            for (int r = 0; r < 4; ++r)
                pacc[nt] += fmaxf(acc[r] + bias[nt], 0.f);
        }
    }
#pragma unroll
    for (int nt = 0; nt < 8; ++nt) psum[(w * 8 + nt) * 64 + lane] = pacc[nt];
    __syncthreads();
    if (t < 128) {
        int nt = t >> 4, m2 = t & 15;
        float s = 0.f;
#pragma unroll
        for (int ww = 0; ww < 4; ++ww)
#pragma unroll
            for (int q = 0; q < 4; ++q)
                s += psum[(ww * 8 + nt) * 64 + q * 16 + m2];
        partial[blockIdx.x * C_OUT + t] = s;   // ch = nt*16 + m2 = t
    }
}

// ---------- final: mean + FC -> 2 outputs (dtype per flag) ----------
__global__ __launch_bounds__(512) void k_final(const float* __restrict__ partial,
                                               const float* __restrict__ fcWc,
                                               const float* __restrict__ fcbc,
                                               void* __restrict__ out,
                                               const int* __restrict__ flags) {
    __shared__ float sm[512];
    __shared__ float red[256];
    int t = threadIdx.x;
    int f = t & 127, c = t >> 7;
    float s = 0.f;
    for (int b = c; b < G2F; b += 4) s += partial[b * 128 + f];
    sm[t] = s;
    __syncthreads();
    if (t < 128) {
        float gm = (sm[t] + sm[t + 128] + sm[t + 256] + sm[t + 384]) * (1.0f / (float)N_NODES);
        red[t] = gm * fcWc[t];
        red[128 + t] = gm * fcWc[128 + t];
    }
    __syncthreads();
    for (int off = 64; off >= 1; off >>= 1) {
        if (t < off) {
            red[t] += red[t + off];
            red[128 + t] += red[128 + t + off];
        }
        __syncthreads();
    }
    if (t == 0) {
        float o0 = red[0] + fcbc[0];
        float o1 = red[128] + fcbc[1];
        if (flags[0]) {
            u16* ob = (u16*)out;
            ob[0] = f2bf(o0);
            ob[1] = f2bf(o1);
        } else {
            float* of = (float*)out;
            of[0] = o0;
            of[1] = o1;
        }
    }
}

// ---------- workspace layout (bytes) ----------
// csr int[E + NB*256 + pad] = 13,200,384 B. g1/a1s fp8 (6.4MB each; regions
// keep their old 12.8MB spacing). ebuf dedicated u32[NB*BCAP] (25.6MB).
#define OFF_FLAGS   0u
#define OFF_DINV    512u         // float[N]
#define OFF_ROWPTR  400896u      // int[N+1]
#define OFF_BCNT    801280u      // u32[NB]
#define OFF_CSR     1201664u     // int[3300096]
#define OFF_H1      14402560u    // fp8[N*64]  (g1 = 16*dinv*h1, permuted bytes)
#define OFF_A1      27202560u    // fp8[N*64]  (a1s, permuted bytes)
#define OFF_AGG     40002560u    // bf16[N*64]
#define OFF_PART    52802560u    // float[G2F*128]
#define OFF_W1C     53122560u    // u16[256*64] (MFMA frag order)
#define OFF_W2C     53155328u    // u16[64*128] (MFMA frag order)
#define OFF_B1C     53171712u    // float[64]
#define OFF_B2C     53171968u    // float[128]
#define OFF_FCWC    53172480u    // float[256]
#define OFF_FCBC    53173504u    // float[2]
#define OFF_EBUF    53174272u    // u32[NB*BCAP] = 25,624,576 B (ends ~78.8MB)

extern "C" void kernel_launch(void* const* d_in, const int* in_sizes, int n_in,
                              void* d_out, int out_size, void* d_ws, size_t ws_size,
                              hipStream_t stream) {
    (void)in_sizes; (void)n_in; (void)out_size; (void)ws_size;
    const void* x   = d_in[0];
    const int*  ei  = (const int*)d_in[1];
    const void* W1  = d_in[2];
    const void* b1  = d_in[3];
    const void* W2  = d_in[4];
    const void* b2  = d_in[5];
    const void* fcW = d_in[6];
    const void* fcb = d_in[7];

    char* ws = (char*)d_ws;
    int*   flags  = (int*)(ws + OFF_FLAGS);
    float* dinv   = (float*)(ws + OFF_DINV);
    int*   rowptr = (int*)(ws + OFF_ROWPTR);
    u32*   bcnt   = (u32*)(ws + OFF_BCNT);
    int*   csr    = (int*)(ws + OFF_CSR);
    u8*    g1     = (u8*)(ws + OFF_H1);
    u8*    a1s    = (u8*)(ws + OFF_A1);
    u16*   aggb   = (u16*)(ws + OFF_AGG);
    u32*   ebuf   = (u32*)(ws + OFF_EBUF);
    float* partial= (float*)(ws + OFF_PART);
    u16*   W1m    = (u16*)(ws + OFF_W1C);
    u16*   W2m    = (u16*)(ws + OFF_W2C);
    float* b1c    = (float*)(ws + OFF_B1C);
    float* b2c    = (float*)(ws + OFF_B2C);
    float* fcWc   = (float*)(ws + OFF_FCWC);
    float* fcbc   = (float*)(ws + OFF_FCBC);

    k_prep<<<96, 256, 0, stream>>>(x, ei, W1, W2, b1, b2, fcW, fcb,
                                   flags, W1m, W2m, bcnt, b1c, b2c, fcWc, fcbc);
    k_scatter1<<<NB, 512, 0, stream>>>(ei, flags, bcnt, ebuf);
    k_scatter2<<<NB, 256, 0, stream>>>(bcnt, ebuf, rowptr, dinv, csr);
    k_gemm1<<<(N_NODES + 127) / 128, 256, 0, stream>>>(x, W1m, dinv, g1, flags);
    k_gatherM<0><<<G_GM, 256, 0, stream>>>(rowptr, csr, dinv, g1, b1c, (void*)a1s);
    k_gatherM<1><<<G_GM, 256, 0, stream>>>(rowptr, csr, dinv, a1s, b2c, (void*)aggb);
    k_fused2<<<G2F, 256, 0, stream>>>(aggb, W2m, b2c, partial);
    k_final<<<1, 512, 0, stream>>>(partial, fcWc, fcbc, (void*)d_out, flags);
}